// Round 8
// baseline (459.293 us; speedup 1.0000x reference)
//
#include <hip/hip_runtime.h>
#include <math.h>

#define B_ 4
#define L_ 2048
#define G_ 256
#define T_ 2304          // G_ + L_
#define DM 1024
#define DINNER 2048
#define NH 16
#define HD 128
#define NSTATE 64
#define CONVD 2176       // DINNER + 2*NSTATE
#define DPROJ 4240       // 2*DINNER + 2*NSTATE + NH
#define NPROJ_PAD 4352   // DPROJ padded to 128
#define NCHUNK 9
#define CK 256
#define EPSV 1e-5f
#define CROWS 16         // conv rows per thread
#define CONVBLKS 612     // (B_*T_/CROWS)*272/256

typedef unsigned short bf16t;
using bf16x8 = __attribute__((ext_vector_type(8))) short;
using f32x4  = __attribute__((ext_vector_type(4))) float;

__device__ __forceinline__ float bf2f(bf16t u) {
  return __uint_as_float(((unsigned int)u) << 16);
}
__device__ __forceinline__ bf16t f2bf(float f) {
  unsigned int u = __float_as_uint(f);
  u += 0x7FFFu + ((u >> 16) & 1u);
  return (bf16t)(u >> 16);
}

__device__ __forceinline__ void g2lds16(const bf16t* g, short* l) {
  __builtin_amdgcn_global_load_lds(
      (const __attribute__((address_space(1))) unsigned int*)g,
      (__attribute__((address_space(3))) unsigned int*)l, 16, 0, 0);
}

// XCD-chunked bijective block swizzle (requires gridDim.x*gridDim.y % 8 == 0).
__device__ __forceinline__ int2 xcd_swz(int tiles_n) {
  int gx = gridDim.x, gy = gridDim.y;
  int id = blockIdx.y * gx + blockIdx.x;
  int cpx = (gx * gy) >> 3;
  int L = (id & 7) * cpx + (id >> 3);
  return make_int2(L % tiles_n, L / tiles_n);   // (nhat, mhat)
}

// ---------- block-wide reduction of two values (blockDim == 256) ----------
__device__ __forceinline__ float2 block_reduce2(float a, float b) {
  __shared__ float sa[4], sb[4];
  #pragma unroll
  for (int off = 32; off > 0; off >>= 1) {
    a += __shfl_down(a, off, 64);
    b += __shfl_down(b, off, 64);
  }
  int lane = threadIdx.x & 63, wid = threadIdx.x >> 6;
  if (lane == 0) { sa[wid] = a; sb[wid] = b; }
  __syncthreads();
  return make_float2(sa[0] + sa[1] + sa[2] + sa[3], sb[0] + sb[1] + sb[2] + sb[3]);
}

// ---------- LN1/LN2+concat (blocks 0..9215) fused with in_proj weight cvt ----------
__global__ __launch_bounds__(256) void ln_cvt_kernel(
    const float* __restrict__ localr, const float* __restrict__ globalr,
    const float* __restrict__ w1, const float* __restrict__ b1,
    const float* __restrict__ w2, const float* __restrict__ b2,
    bf16t* __restrict__ x, const float* __restrict__ inpw,
    bf16t* __restrict__ inpw_bf) {
  int blk = blockIdx.x;
  if (blk < B_ * T_) {
    int t = blk % T_, b = blk / T_;
    const float *src, *w, *bb;
    if (t < G_) { src = globalr + ((long)b * G_ + t) * DM;        w = w2; bb = b2; }
    else        { src = localr  + ((long)b * L_ + (t - G_)) * DM; w = w1; bb = b1; }
    int d = threadIdx.x * 4;
    float4 v = *(const float4*)&src[d];
    float s = v.x + v.y + v.z + v.w;
    float sq = v.x * v.x + v.y * v.y + v.z * v.z + v.w * v.w;
    float2 r2 = block_reduce2(s, sq);
    float mu = r2.x * (1.f / DM);
    float var = r2.y * (1.f / DM) - mu * mu;
    float rstd = rsqrtf(var + EPSV);
    float4 wv = *(const float4*)&w[d];
    float4 bv = *(const float4*)&bb[d];
    ushort4 o;
    o.x = f2bf((v.x - mu) * rstd * wv.x + bv.x);
    o.y = f2bf((v.y - mu) * rstd * wv.y + bv.y);
    o.z = f2bf((v.z - mu) * rstd * wv.z + bv.z);
    o.w = f2bf((v.w - mu) * rstd * wv.w + bv.w);
    *(ushort4*)&x[(long)blk * DM + d] = o;
  } else {
    long i = (long)(blk - B_ * T_) * 1024 + threadIdx.x * 4;
    const long nreal = (long)DPROJ * DM, ntot = (long)NPROJ_PAD * DM;
    if (i < ntot) {
      ushort4 o = {0, 0, 0, 0};
      if (i < nreal) {
        float4 v = *(const float4*)&inpw[i];
        o.x = f2bf(v.x); o.y = f2bf(v.y); o.z = f2bf(v.z); o.w = f2bf(v.w);
      }
      *(ushort4*)&inpw_bf[i] = o;
    }
  }
}

// ---------- wide GEMM: 256x128 tile, 8 waves (4M x 2N), BK=32, 2-phase/K-tile ----------
// 2 blocks/CU (72 KiB LDS) so barrier/vmcnt stalls of one block are filled by the
// other. A: 3 slots [256][32]; B: 3 slots [128][32] -- BOTH staged 2 tiles ahead
// into slot (t+2)%3 (== (t-1)%3, last read >=2 barriers earlier; no same-slot
// write-while-read race). Counted vmcnt(3)/tile = next tile's 3 loads in flight.
// Source-swizzled (T2): 16B group g of row r stored at g^(r&3).
// EPI 0: in_proj (z/xpre/dt routing); EPI 1: plain bf16 C (out_proj, OFFS remap);
// EPI 2: f32 C + bias + residual (ffn2 -> d_out).
template<int EPI, bool OFFS, int K>
__global__ __launch_bounds__(512, 4) void gemm_wide(
    const bf16t* __restrict__ A, const bf16t* __restrict__ W,
    bf16t* __restrict__ Cb, bf16t* __restrict__ z, bf16t* __restrict__ xpre,
    float* __restrict__ dtr, const float* __restrict__ bias,
    const bf16t* __restrict__ res, float* __restrict__ Cf, int N) {
  __shared__ short LDS8[36864];   // 72 KiB: A slots 0/8192/16384, B 24576+{0,4096,8192}
  int tid = threadIdx.x;
  int lane = tid & 63, w = tid >> 6;
  int wm = w >> 1, wn = w & 1;
  int l15 = lane & 15;
  int2 sz = xcd_swz(gridDim.x);
  int bn = sz.x * 128, bm = sz.y * 256;
  if (EPI == 0 && bn < DINNER && (bm % 2304) == 0) return;
  long bmA = OFFS ? ((long)(bm >> 11) * T_ + G_ + (bm & 2047)) : (long)bm;

  // staging: lane -> row_local = lane>>2, stored 16B-group = lane&3;
  // logical col group = (lane&3) ^ (row&3) = (lane&3) ^ ((lane>>2)&3)
  int csub = ((lane & 3) ^ ((lane >> 2) & 3)) * 8;
  const bf16t* srcA = A + (bmA + w * 16 + (lane >> 2)) * (long)K + csub;
  const bf16t* srcW = W + (long)(bn + w * 16 + (lane >> 2)) * K + csub;
  int stageDst = w * 512 + lane * 8;     // shorts; wave covers 16 rows x 32 shorts

  // frag-read offset (shorts): row-part l15, stored group = (lane>>4) ^ (l15&3)
  int off0 = l15 * 32 + ((lane >> 4) ^ (l15 & 3)) * 8;

  f32x4 acc[4][4] = {};
  bf16x8 af[4], bq[4];

#define STAGEA(gsrc, ldsoff) do { \
    g2lds16((gsrc), LDS8 + (ldsoff) + stageDst); \
    g2lds16((gsrc) + 128 * (long)K, LDS8 + (ldsoff) + stageDst + 4096); } while (0)
#define STAGEB(gsrc, ldsoff) g2lds16((gsrc), LDS8 + (ldsoff) + stageDst)

  // prologue: tiles 0 and 1; vmcnt(3) -> tile0's 3 loads landed (tile1's in flight)
  STAGEA(srcA, 0);
  STAGEB(srcW, 24576);
  STAGEA(srcA + 32, 8192);
  STAGEB(srcW + 32, 24576 + 4096);
  asm volatile("s_waitcnt vmcnt(3)" ::: "memory");
  __builtin_amdgcn_s_barrier();

  const int nt = K >> 5;
  for (int t = 0; t < nt; ++t) {
    const short* aB = LDS8 + (t % 3) * 8192 + wm * 2048;
    const short* bB = LDS8 + 24576 + (t % 3) * 4096 + wn * 2048;
    int nsA = ((t + 2) % 3) * 8192;
    int nsB = 24576 + ((t + 2) % 3) * 4096;

    // ---- phase 1: read A(mi0-3)+B(ni0-1); MFMA half; stage A(t+2) ----
    #pragma unroll
    for (int mi = 0; mi < 4; mi++) af[mi] = *(const bf16x8*)&aB[mi * 512 + off0];
    #pragma unroll
    for (int ni = 0; ni < 2; ni++) bq[ni] = *(const bf16x8*)&bB[ni * 512 + off0];
    if (t + 2 < nt) STAGEA(srcA + (t + 2) * 32, nsA);
    __builtin_amdgcn_s_barrier();
    __builtin_amdgcn_s_setprio(1);
    #pragma unroll
    for (int mi = 0; mi < 4; mi++)
      #pragma unroll
      for (int ni = 0; ni < 2; ni++)
        acc[mi][ni] = __builtin_amdgcn_mfma_f32_16x16x32_bf16(af[mi], bq[ni], acc[mi][ni], 0, 0, 0);
    __builtin_amdgcn_s_setprio(0);
    __builtin_amdgcn_s_barrier();

    // ---- phase 2: read B(ni2-3); MFMA half; stage B(t+2); counted vmcnt ----
    #pragma unroll
    for (int ni = 2; ni < 4; ni++) bq[ni] = *(const bf16x8*)&bB[ni * 512 + off0];
    if (t + 2 < nt) STAGEB(srcW + (t + 2) * 32, nsB);
    __builtin_amdgcn_s_barrier();
    __builtin_amdgcn_s_setprio(1);
    #pragma unroll
    for (int mi = 0; mi < 4; mi++)
      #pragma unroll
      for (int ni = 2; ni < 4; ni++)
        acc[mi][ni] = __builtin_amdgcn_mfma_f32_16x16x32_bf16(af[mi], bq[ni], acc[mi][ni], 0, 0, 0);
    __builtin_amdgcn_s_setprio(0);
    if (t + 2 < nt)      asm volatile("s_waitcnt vmcnt(3)" ::: "memory");
    else if (t + 1 < nt) asm volatile("s_waitcnt vmcnt(0)" ::: "memory");
    __builtin_amdgcn_s_barrier();
  }
#undef STAGEA
#undef STAGEB

  // ---- epilogue ----
  if (EPI == 0 && bn == 4224) {
    if (wn == 0) {
      #pragma unroll
      for (int mi = 0; mi < 4; mi++)
        #pragma unroll
        for (int r = 0; r < 4; r++) {
          int row = bm + wm * 64 + mi * 16 + (lane >> 4) * 4 + r;
          dtr[(long)row * NH + l15] = acc[mi][0][r];
        }
    }
    return;
  }

  if (EPI == 2) {
    // f32 + bias + residual (ffn2): 4 passes of 64 rows (fits LDS)
    float* Cs32 = (float*)LDS8;               // [64][136] f32 = 34816 B
    #pragma unroll
    for (int pass = 0; pass < 4; pass++) {
      __syncthreads();
      if (wm == pass) {
        #pragma unroll
        for (int mi = 0; mi < 4; mi++)
          #pragma unroll
          for (int ni = 0; ni < 4; ni++)
            #pragma unroll
            for (int r = 0; r < 4; r++)
              Cs32[(mi * 16 + (lane >> 4) * 4 + r) * 136 + wn * 64 + ni * 16 + l15] =
                  acc[mi][ni][r];
      }
      __syncthreads();
      #pragma unroll
      for (int q = 0; q < 2; q++) {
        int idx = q * 512 + tid;             // 64 rows x 16 groups of 8 f32
        int row = idx >> 4, cg = (idx & 15) * 8;
        long grow = bm + pass * 64 + row; int gcol = bn + cg;
        float4 v0 = *(float4*)&Cs32[row * 136 + cg];
        float4 v1 = *(float4*)&Cs32[row * 136 + cg + 4];
        float4 b0 = *(const float4*)&bias[gcol];
        float4 b1 = *(const float4*)&bias[gcol + 4];
        bf16x8 rv = *(const bf16x8*)&res[grow * (long)N + gcol];
        v0.x += b0.x + bf2f((bf16t)rv[0]); v0.y += b0.y + bf2f((bf16t)rv[1]);
        v0.z += b0.z + bf2f((bf16t)rv[2]); v0.w += b0.w + bf2f((bf16t)rv[3]);
        v1.x += b1.x + bf2f((bf16t)rv[4]); v1.y += b1.y + bf2f((bf16t)rv[5]);
        v1.z += b1.z + bf2f((bf16t)rv[6]); v1.w += b1.w + bf2f((bf16t)rv[7]);
        *(float4*)&Cf[grow * (long)N + gcol] = v0;
        *(float4*)&Cf[grow * (long)N + gcol + 4] = v1;
      }
    }
    return;
  }

  // bf16 C via LDS roundtrip: 2 passes of 128 rows ([128][136] bf16 = 34816 B)
  bf16t* Cs = (bf16t*)LDS8;
  #pragma unroll
  for (int pass = 0; pass < 2; pass++) {
    __syncthreads();
    if ((wm >> 1) == pass) {
      #pragma unroll
      for (int mi = 0; mi < 4; mi++)
        #pragma unroll
        for (int ni = 0; ni < 4; ni++)
          #pragma unroll
          for (int r = 0; r < 4; r++)
            Cs[((wm & 1) * 64 + mi * 16 + (lane >> 4) * 4 + r) * 136 + wn * 64 + ni * 16 + l15] =
                f2bf(acc[mi][ni][r]);
    }
    __syncthreads();
    #pragma unroll
    for (int q = 0; q < 4; q++) {
      int idx = q * 512 + tid;
      int row = idx >> 4, cg = idx & 15;
      int gcol = bn + cg * 8;
      long grow = bm + pass * 128 + row;
      bf16x8 v = *(bf16x8*)&Cs[row * 136 + cg * 8];
      if (EPI == 0) {
        if (gcol < DINNER) *(bf16x8*)&z[grow * DINNER + gcol] = v;
        else               *(bf16x8*)&xpre[grow * CONVD + (gcol - DINNER)] = v;
      } else {
        *(bf16x8*)&Cb[grow * (long)N + gcol] = v;
      }
    }
  }
}

// ---------- MFMA bf16 GEMM 128x128 (ffn1: gelu(v+bias)) ----------
template<int EPI>
__global__ __launch_bounds__(256) void gemm_mfma(
    const bf16t* __restrict__ A, const bf16t* __restrict__ W,
    const float* __restrict__ bias, const bf16t* __restrict__ res,
    float* __restrict__ Cf, bf16t* __restrict__ Cb,
    int N, int K) {
  __shared__ __align__(16) short LDS[128 * 136];
  short* As = LDS;              // [128][32]
  short* Ws = LDS + 128 * 32;   // [128][32]
  int tid = threadIdx.x;
  int lane = tid & 63, w = tid >> 6;
  int wr = w >> 1, wc = w & 1;
  int2 sz = xcd_swz(gridDim.x);
  int bn = sz.x * 128, bm = sz.y * 128;

  int r1 = tid >> 2,         s1 = (((tid & 3) ^ ((r1 >> 1) & 3))) * 8;
  int r2 = (tid + 256) >> 2, s2 = (((tid & 3) ^ ((r2 >> 1) & 3))) * 8;
  const bf16t* gA1 = A + (long)(bm + r1) * K + s1;
  const bf16t* gA2 = A + (long)(bm + r2) * K + s2;
  const bf16t* gW1 = W + (long)(bn + r1) * K + s1;
  const bf16t* gW2 = W + (long)(bn + r2) * K + s2;
  short* lA1 = As + tid * 8;
  short* lA2 = As + (tid + 256) * 8;
  short* lW1 = Ws + tid * 8;
  short* lW2 = Ws + (tid + 256) * 8;

  int arow = wr * 64 + (lane & 15);
  int brow = wc * 64 + (lane & 15);
  int koff = (((lane >> 4) ^ (((lane & 15) >> 1) & 3))) * 8;

  f32x4 acc[4][4] = {};
  for (int k0 = 0; k0 < K; k0 += 32) {
    g2lds16(gA1 + k0, lA1);
    g2lds16(gA2 + k0, lA2);
    g2lds16(gW1 + k0, lW1);
    g2lds16(gW2 + k0, lW2);
    __syncthreads();
    bf16x8 af[4], bf[4];
    #pragma unroll
    for (int mi = 0; mi < 4; mi++) af[mi] = *(bf16x8*)&As[(arow + mi * 16) * 32 + koff];
    #pragma unroll
    for (int ni = 0; ni < 4; ni++) bf[ni] = *(bf16x8*)&Ws[(brow + ni * 16) * 32 + koff];
    #pragma unroll
    for (int mi = 0; mi < 4; mi++)
      #pragma unroll
      for (int ni = 0; ni < 4; ni++)
        acc[mi][ni] = __builtin_amdgcn_mfma_f32_16x16x32_bf16(af[mi], bf[ni], acc[mi][ni], 0, 0, 0);
    __syncthreads();
  }

  int rb = wr * 64 + (lane >> 4) * 4;
  int cb = wc * 64 + (lane & 15);

  __syncthreads();
  bf16t* Cs = (bf16t*)LDS;                     // [128][136]
  #pragma unroll
  for (int mi = 0; mi < 4; mi++)
    #pragma unroll
    for (int ni = 0; ni < 4; ni++)
      #pragma unroll
      for (int r = 0; r < 4; r++) {
        float v = acc[mi][ni][r];
        if (EPI == 2) {
          v += bias[bn + cb + ni * 16];
          v = 0.5f * v * (1.f + erff(v * 0.70710678118f));
        }
        Cs[(rb + mi * 16 + r) * 136 + cb + ni * 16] = f2bf(v);
      }
  __syncthreads();
  #pragma unroll
  for (int pass = 0; pass < 8; pass++) {
    int row = pass * 16 + (tid >> 4);
    int col = (tid & 15) * 8;
    bf16x8 vv = *(bf16x8*)&Cs[row * 136 + col];
    long grow = bm + row; int gcol = bn + col;
    *(bf16x8*)&Cb[grow * N + gcol] = vv;
  }
}

// ---------- merged: causal conv(4)+bias+silu  AND  dt softplus + chunk cumsum ----------
__global__ __launch_bounds__(256) void conv_cumsum_kernel(
    const bf16t* __restrict__ xpre, const float* __restrict__ cw,
    const float* __restrict__ cb, bf16t* __restrict__ out,
    const float* __restrict__ dtraw, const float* __restrict__ dt_bias,
    const float* __restrict__ A_log, float* __restrict__ dt,
    float* __restrict__ Acum) {
  if (blockIdx.x < CONVBLKS) {
    int gt = blockIdx.x * 256 + threadIdx.x;    // < 576*272
    int cg = gt % 272; int rt = gt / 272;
    int c0 = cg * 8;
    long r0 = (long)rt * CROWS;
    int t0 = (int)(r0 % T_);

    float wreg[4][8];
    #pragma unroll
    for (int j = 0; j < 8; j++) {
      float4 wa = *(const float4*)&cw[(c0 + j) * 4];
      wreg[0][j] = wa.x; wreg[1][j] = wa.y; wreg[2][j] = wa.z; wreg[3][j] = wa.w;
    }
    float4 cb0 = *(const float4*)&cb[c0];
    float4 cb1 = *(const float4*)&cb[c0 + 4];
    float bias[8] = {cb0.x, cb0.y, cb0.z, cb0.w, cb1.x, cb1.y, cb1.z, cb1.w};

    bf16x8 win[4];
    #pragma unroll
    for (int i = 0; i < 3; i++) {
      if (t0 - 3 + i >= 0) win[i] = *(const bf16x8*)&xpre[(r0 - 3 + i) * CONVD + c0];
      else                 win[i] = bf16x8{0,0,0,0,0,0,0,0};
    }

    #pragma unroll
    for (int k = 0; k < CROWS; k++) {
      win[3] = *(const bf16x8*)&xpre[(r0 + k) * CONVD + c0];
      float acc[8];
      #pragma unroll
      for (int j = 0; j < 8; j++) acc[j] = bias[j];
      #pragma unroll
      for (int i = 0; i < 4; i++)
        #pragma unroll
        for (int j = 0; j < 8; j++)
          acc[j] += bf2f((bf16t)win[i][j]) * wreg[i][j];
      bf16x8 o;
      #pragma unroll
      for (int j = 0; j < 8; j++) {
        float s = acc[j] / (1.f + __expf(-acc[j]));
        o[j] = (short)f2bf(s);
      }
      *(bf16x8*)&out[(r0 + k) * CONVD + c0] = o;
      win[0] = win[1]; win[1] = win[2]; win[2] = win[3];
    }
  } else {
    int bid = blockIdx.x - CONVBLKS;      // (b*NH+h)*NCHUNK + c
    int c = bid % NCHUNK; int hh = bid / NCHUNK;
    int h = hh % NH; int b = hh / NH;
    int k = threadIdx.x;
    float a = -__expf(A_log[h]);
    long t = (long)b * T_ + c * CK + k;
    float v0 = dtraw[t * NH + h] + dt_bias[h];
    float dtv = (v0 > 20.f) ? v0 : log1pf(__expf(v0));
    dt[t * NH + h] = dtv;
    float v = dtv * a;
    __shared__ float buf[2][CK];
    int cur = 0;
    buf[0][k] = v; __syncthreads();
    for (int off = 1; off < CK; off <<= 1) {
      float tv = buf[cur][k];
      if (k >= off) tv += buf[cur][k - off];
      buf[1 - cur][k] = tv; cur ^= 1; __syncthreads();
    }
    Acum[(long)bid * CK + k] = buf[cur][k];
  }
}

// ---------- per-chunk states via MFMA (chunks 0..7 only; chunk 8 unused) ----------
__global__ __launch_bounds__(256) void chunk_states_kernel(
    const bf16t* __restrict__ xbc, const float* __restrict__ dt,
    const float* __restrict__ Acum, float* __restrict__ cs) {
  int bid = blockIdx.x;                 // 512
  int h = bid & 15; int bc = bid >> 4;
  int c = bc & 7; int b = bc >> 3;
  int tid = threadIdx.x;
  int lane = tid & 63, w = tid >> 6;
  long tch = (long)b * T_ + c * CK;
  int acb = ((b * NH + h) * NCHUNK + c) * CK;
  float Alast = Acum[acb + CK - 1];

  __shared__ bf16t Xt[128][72];
  __shared__ bf16t Bt[64][72];
  __shared__ float wkv[256];
  // preload full chunk decay*dt weights once (replaces per-kb barrier+gather)
  wkv[tid] = __expf(Alast - Acum[acb + tid]) * dt[(tch + tid) * NH + h];

  f32x4 acc[8] = {};
  for (int kb = 0; kb < 4; kb++) {
    int s0 = kb * 64;
    __syncthreads();
    // Xt: 4-col packed ds_write_b64 transpose staging
    for (int e = tid; e < 16 * 32; e += 256) {
      int s4 = (e & 15) * 4, p4 = e >> 4;
      const bf16t* base = &xbc[(tch + s0 + s4) * CONVD + h * HD + p4 * 4];
      ushort4 u0 = *(const ushort4*)(base);
      ushort4 u1 = *(const ushort4*)(base + CONVD);
      ushort4 u2 = *(const ushort4*)(base + 2 * CONVD);
      ushort4 u3 = *(const ushort4*)(base + 3 * CONVD);
      float w0 = wkv[s0 + s4], w1 = wkv[s0 + s4 + 1];
      float w2 = wkv[s0 + s4 + 2], w3 = wkv[s0 + s4 + 3];
      ushort4 pk;
      pk.x = f2bf(bf2f(u0.x) * w0); pk.y = f2bf(bf2f(u1.x) * w1);
      pk.z = f2bf(bf2f(u2.x) * w2); pk.w = f2bf(bf2f(u3.x) * w3);
      *(ushort4*)&Xt[p4 * 4 + 0][s4] = pk;
      pk.x = f2bf(bf2f(u0.y) * w0); pk.y = f2bf(bf2f(u1.y) * w1);
      pk.z = f2bf(bf2f(u2.y) * w2); pk.w = f2bf(bf2f(u3.y) * w3);
      *(ushort4*)&Xt[p4 * 4 + 1][s4] = pk;
      pk.x = f2bf(bf2f(u0.z) * w0); pk.y = f2bf(bf2f(u1.z) * w1);
      pk.z = f2bf(bf2f(u2.z) * w2); pk.w = f2bf(bf2f(u3.z) * w3);
      *(ushort4*)&Xt[p4 * 4 + 2][s4] = pk;
      pk.x = f2bf(bf2f(u0.w) * w0); pk.y = f2bf(bf2f(u1.w) * w1);
      pk.z = f2bf(bf2f(u2.w) * w2); pk.w = f2bf(bf2f(u3.w) * w3);
      *(ushort4*)&Xt[p4 * 4 + 3][s4] = pk;
    }
    // Bt: same packing, no scale
    for (int e = tid; e < 16 * 16; e += 256) {
      int s4 = (e & 15) * 4, n4 = e >> 4;
      const bf16t* base = &xbc[(tch + s0 + s4) * CONVD + DINNER + n4 * 4];
      ushort4 u0 = *(const ushort4*)(base);
      ushort4 u1 = *(const ushort4*)(base + CONVD);
      ushort4 u2 = *(const ushort4*)(base + 2 * CONVD);
      ushort4 u3 = *(const ushort4*)(base + 3 * CONVD);
      ushort4 pk;
      pk.x = u0.x; pk.y = u1.x; pk.z = u2.x; pk.w = u3.x;
      *(ushort4*)&Bt[n4 * 4 + 0][s4] = pk;
      pk.x = u0.y; pk.y = u1.y; pk.z = u2.y; pk.w = u3.y;
      *(ushort4*)&Bt[n4 * 4 + 1][s4] = pk;
      pk.x = u0.z; pk.y = u1.z; pk.z = u2.z; pk.w = u3.z;
      *(ushort4*)&Bt[n4 * 4 + 2][s4] = pk;
      pk.x = u0.w; pk.y = u1.w; pk.z = u2.w; pk.w = u3.w;
      *(ushort4*)&Bt[n4 * 4 + 3][s4] = pk;
    }
    __syncthreads();
    #pragma unroll
    for (int ks = 0; ks < 2; ks++) {
      int koff = (lane >> 4) * 8 + ks * 32;
      bf16x8 bfr = *(bf16x8*)&Bt[w * 16 + (lane & 15)][koff];
      #pragma unroll
      for (int mi = 0; mi < 8; mi++) {
        bf16x8 af = *(bf16x8*)&Xt[mi * 16 + (lane & 15)][koff];
        acc[mi] = __builtin_amdgcn_mfma_f32_16x16x32_bf16(af, bfr, acc[mi], 0, 0, 0);
      }
    }
  }
  int cbid = (b * NCHUNK + c) * NH + h;
  float* out = cs + (long)cbid * HD * NSTATE;
  int n = w * 16 + (lane & 15);
  #pragma unroll
  for (int mi = 0; mi < 8; mi++) {
    #pragma unroll
    for (int r = 0; r < 4; r++) {
      int p = mi * 16 + (lane >> 4) * 4 + r;
      out[p * NSTATE + n] = acc[mi][r];
    }
  }
}

// ---------- sequential inter-chunk recurrence, IN PLACE ----------
__global__ __launch_bounds__(256) void state_pass_kernel(
    float* __restrict__ cs, const float* __restrict__ Acum) {
  int bh = blockIdx.x;                  // b*NH + h
  int b = bh / NH, h = bh % NH;
  int e0 = blockIdx.y * 1024 + threadIdx.x;
  for (int q = 0; q < 4; q++) {
    int e = e0 + q * 256;
    float s = 0.f;
    for (int c = 0; c < NCHUNK; c++) {
      long idx = ((long)(b * NCHUNK + c) * NH + h) * (HD * NSTATE) + e;
      if (c < NCHUNK - 1) {
        float tmp = cs[idx];
        cs[idx] = s;
        float g = __expf(Acum[((b * NH + h) * NCHUNK + c) * CK + CK - 1]);
        s = s * g + tmp;
      } else {
        cs[idx] = s;
      }
    }
  }
}

// ---------- SSD Y via MFMA (chunks 1..8; chunk 0's Y is discarded downstream) ----------
__global__ __launch_bounds__(256) void ssd_y_kernel(
    const bf16t* __restrict__ xbc, const float* __restrict__ dt,
    const float* __restrict__ Acum, const float* __restrict__ sin_,
    const float* __restrict__ Dskip, bf16t* __restrict__ Y) {
  int bid = blockIdx.x;                 // 512
  int h = bid & 15; int bc = bid >> 4;
  int c = 1 + (bc & 7); int b = bc >> 3;
  int rt = blockIdx.y;
  int tid = threadIdx.x;
  int lane = tid & 63, w = tid >> 6;
  int wr = w >> 1, wc = w & 1;
  long tch = (long)b * T_ + c * CK;
  long tbase = tch + rt * 128;
  int acb = ((b * NH + h) * NCHUNK + c) * CK;

  __shared__ bf16t Cs[128][72];
  __shared__ bf16t Bs[64][72];
  __shared__ __align__(16) bf16t XtSm[2][128][72];   // Xt | Sm; reused as f32 pad for Y-write
  bf16t (*Xt)[72] = XtSm[0];
  bf16t (*Sm)[72] = XtSm[1];
  __shared__ float Acv[256];
  __shared__ float dtv[256];

  for (int e = tid; e < 128 * 8; e += 256) {
    int row = e >> 3, seg = (e & 7) * 8;
    *(bf16x8*)&Cs[row][seg] =
        *(const bf16x8*)&xbc[(tbase + row) * CONVD + DINNER + NSTATE + seg];
  }
  // preload full chunk Acum and dt once (replaces per-sb barrier+gather)
  Acv[tid] = Acum[acb + tid];
  dtv[tid] = dt[(tch + tid) * NH + h];
  const float* Ak = Acv + rt * 128;

  f32x4 acc[4][4] = {};
  int nsb = 2 * (rt + 1);
  for (int sb = 0; sb < nsb; sb++) {
    int s0 = sb * 64;
    __syncthreads();
    for (int e = tid; e < 64 * 8; e += 256) {
      int row = e >> 3, seg = (e & 7) * 8;
      *(bf16x8*)&Bs[row][seg] =
          *(const bf16x8*)&xbc[(tch + s0 + row) * CONVD + DINNER + seg];
    }
    // Xt: 4-col packed ds_write_b64 transpose staging (scaled by dt)
    for (int e = tid; e < 16 * 32; e += 256) {
      int s4 = (e & 15) * 4, p4 = e >> 4;
      const bf16t* base = &xbc[(tch + s0 + s4) * CONVD + h * HD + p4 * 4];
      ushort4 u0 = *(const ushort4*)(base);
      ushort4 u1 = *(const ushort4*)(base + CONVD);
      ushort4 u2 = *(const ushort4*)(base + 2 * CONVD);
      ushort4 u3 = *(const ushort4*)(base + 3 * CONVD);
      float d0 = dtv[s0 + s4], d1 = dtv[s0 + s4 + 1];
      float d2 = dtv[s0 + s4 + 2], d3 = dtv[s0 + s4 + 3];
      ushort4 pk;
      pk.x = f2bf(bf2f(u0.x) * d0); pk.y = f2bf(bf2f(u1.x) * d1);
      pk.z = f2bf(bf2f(u2.x) * d2); pk.w = f2bf(bf2f(u3.x) * d3);
      *(ushort4*)&Xt[p4 * 4 + 0][s4] = pk;
      pk.x = f2bf(bf2f(u0.y) * d0); pk.y = f2bf(bf2f(u1.y) * d1);
      pk.z = f2bf(bf2f(u2.y) * d2); pk.w = f2bf(bf2f(u3.y) * d3);
      *(ushort4*)&Xt[p4 * 4 + 1][s4] = pk;
      pk.x = f2bf(bf2f(u0.z) * d0); pk.y = f2bf(bf2f(u1.z) * d1);
      pk.z = f2bf(bf2f(u2.z) * d2); pk.w = f2bf(bf2f(u3.z) * d3);
      *(ushort4*)&Xt[p4 * 4 + 2][s4] = pk;
      pk.x = f2bf(bf2f(u0.w) * d0); pk.y = f2bf(bf2f(u1.w) * d1);
      pk.z = f2bf(bf2f(u2.w) * d2); pk.w = f2bf(bf2f(u3.w) * d3);
      *(ushort4*)&Xt[p4 * 4 + 3][s4] = pk;
    }
    __syncthreads();
    {
      f32x4 sacc[2][4] = {};
      int rw0 = w * 32;
      #pragma unroll
      for (int ks = 0; ks < 2; ks++) {
        int koff = (lane >> 4) * 8 + ks * 32;
        bf16x8 a0 = *(bf16x8*)&Cs[rw0 + (lane & 15)][koff];
        bf16x8 a1 = *(bf16x8*)&Cs[rw0 + 16 + (lane & 15)][koff];
        #pragma unroll
        for (int ni = 0; ni < 4; ni++) {
          bf16x8 bfr = *(bf16x8*)&Bs[ni * 16 + (lane & 15)][koff];
          sacc[0][ni] = __builtin_amdgcn_mfma_f32_16x16x32_bf16(a0, bfr, sacc[0][ni], 0, 0, 0);
          sacc[1][ni] = __builtin_amdgcn_mfma_f32_16x16x32_bf16(a1, bfr, sacc[1][ni], 0, 0, 0);
        }
      }
      #pragma unroll
      for (int mi = 0; mi < 2; mi++) {
        #pragma unroll
        for (int ni = 0; ni < 4; ni++) {
          #pragma unroll
          for (int r = 0; r < 4; r++) {
            int row = rw0 + mi * 16 + (lane >> 4) * 4 + r;
            int scol = ni * 16 + (lane & 15);
            int kglob = rt * 128 + row;
            int sglob = s0 + scol;
            float val = 0.f;
            if (sglob <= kglob) val = sacc[mi][ni][r] * __expf(Ak[row] - Acv[s0 + scol]);
            Sm[row][scol] = f2bf(val);
          }
        }
      }
    }
    __syncthreads();
    #pragma unroll
    for (int ks = 0; ks < 2; ks++) {
      int koff = (lane >> 4) * 8 + ks * 32;
      bf16x8 af[4], bfr[4];
      #pragma unroll
      for (int mi = 0; mi < 4; mi++) af[mi] = *(bf16x8*)&Sm[wr * 64 + mi * 16 + (lane & 15)][koff];
      #pragma unroll
      for (int ni = 0; ni < 4; ni++) bfr[ni] = *(bf16x8*)&Xt[wc * 64 + ni * 16 + (lane & 15)][koff];
      #pragma unroll
      for (int mi = 0; mi < 4; mi++)
        #pragma unroll
        for (int ni = 0; ni < 4; ni++)
          acc[mi][ni] = __builtin_amdgcn_mfma_f32_16x16x32_bf16(af[mi], bfr[ni], acc[mi][ni], 0, 0, 0);
    }
  }

  float ekr[16];
  #pragma unroll
  for (int mi = 0; mi < 4; mi++)
    #pragma unroll
    for (int r = 0; r < 4; r++)
      ekr[mi * 4 + r] = __expf(Ak[wr * 64 + mi * 16 + (lane >> 4) * 4 + r]);

  int cbid = (b * NCHUNK + c) * NH + h;
  const float* sinb = sin_ + (long)cbid * HD * NSTATE;
  #pragma unroll
  for (int ni = 0; ni < 4; ni++) {
    f32x4 offacc[4] = {};
    int p = wc * 64 + ni * 16 + (lane & 15);
    #pragma unroll
    for (int ks = 0; ks < 2; ks++) {
      int koff = (lane >> 4) * 8 + ks * 32;
      const float* srow = sinb + p * NSTATE + koff;
      float4 sa = *(const float4*)srow;
      float4 sbv = *(const float4*)(srow + 4);
      bf16x8 bfr;
      bfr[0] = (short)f2bf(sa.x);  bfr[1] = (short)f2bf(sa.y);
      bfr[2] = (short)f2bf(sa.z);  bfr[3] = (short)f2bf(sa.w);
      bfr[4] = (short)f2bf(sbv.x); bfr[5] = (short)f2bf(sbv.y);
      bfr[6] = (short)f2bf(sbv.z); bfr[7] = (short)f2bf(sbv.w);
      #pragma unroll
      for (int mi = 0; mi < 4; mi++) {
        bf16x8 af = *(bf16x8*)&Cs[wr * 64 + mi * 16 + (lane & 15)][koff];
        offacc[mi] = __builtin_amdgcn_mfma_f32_16x16x32_bf16(af, bfr, offacc[mi], 0, 0, 0);
      }
    }
    #pragma unroll
    for (int mi = 0; mi < 4; mi++)
      #pragma unroll
      for (int r = 0; r < 4; r++)
        acc[mi][ni][r] += ekr[mi * 4 + r] * offacc[mi][r];
  }

  // ---- vectorized Y write: acc (f32) through LDS (dead Xt+Sm), bf16x8 IO ----
  float dsk = Dskip[h];
  float* Sf = (float*)&XtSm[0][0][0];          // [64][130] f32 (33280 B <= 36864)
  #pragma unroll
  for (int rh = 0; rh < 2; rh++) {
    __syncthreads();
    if (wr == rh) {
      #pragma unroll
      for (int mi = 0; mi < 4; mi++)
        #pragma unroll
        for (int ni = 0; ni < 4; ni++)
          #pragma unroll
          for (int r = 0; r < 4; r++)
            Sf[(mi * 16 + (lane >> 4) * 4 + r) * 130 + wc * 64 + ni * 16 + (lane & 15)] =
                acc[mi][ni][r];
    }
    __syncthreads();
    #pragma unroll
    for (int g = 0; g < 4; g++) {
      int idx = g * 256 + tid;                 // 64 rows x 16 col-groups
      int row = idx >> 4, cg = (idx & 15) * 8;
      long t = tbase + rh * 64 + row;
      bf16x8 xv = *(const bf16x8*)&xbc[t * CONVD + h * HD + cg];
      bf16x8 o;
      #pragma unroll
      for (int j = 0; j < 8; j++)
        o[j] = (short)f2bf(Sf[row * 130 + cg + j] + dsk * bf2f((bf16t)xv[j]));
      *(bf16x8*)&Y[t * DINNER + h * HD + cg] = o;
    }
  }
}

// ---------- gate+RMSNorm (local rows only) fused with late weight cvt ----------
__global__ __launch_bounds__(256) void gate_rms_cvt_kernel(
    const bf16t* __restrict__ z, const float* __restrict__ nw,
    bf16t* __restrict__ Y,
    const float* __restrict__ outw, const float* __restrict__ f1w,
    const float* __restrict__ f2w, bf16t* __restrict__ o_out,
    bf16t* __restrict__ o_f1, bf16t* __restrict__ o_f2) {
  int blk = blockIdx.x;
  if (blk < B_ * L_) {
    long r = (long)(blk >> 11) * T_ + G_ + (blk & 2047);
    const bf16t* zrow = z + r * DINNER;
    bf16t* yrow = Y + r * DINNER;
    int tid = threadIdx.x;
    int d = tid * 8;
    bf16x8 zu = *(const bf16x8*)&zrow[d];
    bf16x8 yu = *(const bf16x8*)&yrow[d];
    float v[8]; float sq = 0.f;
    #pragma unroll
    for (int j = 0; j < 8; j++) {
      float z0 = bf2f((bf16t)zu[j]);
      float y0 = bf2f((bf16t)yu[j]) * (z0 / (1.f + __expf(-z0)));
      v[j] = y0; sq += y0 * y0;
    }
    float2 r2 = block_reduce2(sq, 0.f);
    float rms = rsqrtf(r2.x * (1.f / DINNER) + EPSV);
    float4 nw0 = *(const float4*)&nw[d];
    float4 nw1 = *(const float4*)&nw[d + 4];
    float nn[8] = {nw0.x, nw0.y, nw0.z, nw0.w, nw1.x, nw1.y, nw1.z, nw1.w};
    bf16x8 o;
    #pragma unroll
    for (int j = 0; j < 8; j++) o[j] = (short)f2bf(v[j] * rms * nn[j]);
    *(bf16x8*)&yrow[d] = o;
  } else {
    long i = (long)(blk - B_ * L_) * 1024 + threadIdx.x * 4;
    const long n1 = (long)DM * DINNER;          // 2097152
    const long n2 = (long)(DM / 2) * DM;        // 524288
    const float* src; bf16t* dst; long off;
    if (i < n1) { src = outw; dst = o_out; off = i; }
    else if (i < n1 + n2) { src = f1w; dst = o_f1; off = i - n1; }
    else { src = f2w; dst = o_f2; off = i - n1 - n2; }
    float4 v = *(const float4*)&src[off];
    ushort4 o;
    o.x = f2bf(v.x); o.y = f2bf(v.y); o.z = f2bf(v.z); o.w = f2bf(v.w);
    *(ushort4*)&dst[off] = o;
  }
}

// ---------- residual add + LayerNorm3 -> bf16 (mfull compact [8192][1024]) ----------
__global__ __launch_bounds__(256) void res_ln3_kernel(
    const bf16t* __restrict__ mfull, const bf16t* __restrict__ x,
    const float* __restrict__ w3, const float* __restrict__ b3,
    bf16t* __restrict__ x2) {
  int rl = blockIdx.x;                  // b*L_ + tl
  int tl = rl & 2047, b = rl >> 11;
  long rt = (long)b * T_ + G_ + tl;
  const bf16t* m = mfull + (long)rl * DM;
  const bf16t* xr = x + rt * DM;
  int tid = threadIdx.x;
  int d = tid * 4;
  ushort4 mu4 = *(const ushort4*)&m[d];
  ushort4 xu4 = *(const ushort4*)&xr[d];
  float v[4];
  v[0] = bf2f(mu4.x) + bf2f(xu4.x);
  v[1] = bf2f(mu4.y) + bf2f(xu4.y);
  v[2] = bf2f(mu4.z) + bf2f(xu4.z);
  v[3] = bf2f(mu4.w) + bf2f(xu4.w);
  float s = v[0] + v[1] + v[2] + v[3];
  float sq = v[0]*v[0] + v[1]*v[1] + v[2]*v[2] + v[3]*v[3];
  float2 r2 = block_reduce2(s, sq);
  float mu = r2.x * (1.f / DM);
  float var = r2.y * (1.f / DM) - mu * mu;
  float rstd = rsqrtf(var + EPSV);
  float4 w4 = *(const float4*)&w3[d];
  float4 b4 = *(const float4*)&b3[d];
  ushort4 o;
  o.x = f2bf((v[0] - mu) * rstd * w4.x + b4.x);
  o.y = f2bf((v[1] - mu) * rstd * w4.y + b4.y);
  o.z = f2bf((v[2] - mu) * rstd * w4.z + b4.z);
  o.w = f2bf((v[3] - mu) * rstd * w4.w + b4.w);
  *(ushort4*)&x2[(long)rl * DM + d] = o;
}

extern "C" void kernel_launch(void* const* d_in, const int* in_sizes, int n_in,
                              void* d_out, int out_size, void* d_ws, size_t ws_size,
                              hipStream_t stream) {
  const float* localr = (const float*)d_in[0];
  const float* globalr= (const float*)d_in[1];
  const float* n1w = (const float*)d_in[2];
  const float* n1b = (const float*)d_in[3];
  const float* n2w = (const float*)d_in[4];
  const float* n2b = (const float*)d_in[5];
  const float* n3w = (const float*)d_in[6];
  const float* n3b = (const float*)d_in[7];
  const float* inpw= (const float*)d_in[8];
  const float* convw=(const float*)d_in[9];
  const float* convb=(const float*)d_in[10];
  const float* dtb = (const float*)d_in[11];
  const float* alog= (const float*)d_in[12];
  const float* dskp= (const float*)d_in[13];
  const float* ssdw= (const float*)d_in[14];
  const float* outw= (const float*)d_in[15];
  const float* f1w = (const float*)d_in[16];
  const float* f1b = (const float*)d_in[17];
  const float* f2w = (const float*)d_in[18];
  const float* f2b = (const float*)d_in[19];

  // ---- workspace layout (byte offsets); peak ~150 MB ----
  char* ws = (char*)d_ws;
  bf16t* x     = (bf16t*)(ws + 0);             // 9216*1024 bf16
  bf16t* z     = (bf16t*)(ws + 18874368);      // 9216*2048 bf16
  bf16t* mfull = (bf16t*)(ws + 18874368);      //   overlay: 8192*1024 bf16 compact
  bf16t* xpre  = (bf16t*)(ws + 56623104);      // 9216*2176 bf16
  bf16t* Yb    = (bf16t*)(ws + 56623104);      //   overlay: 9216*2048 bf16 (after conv)
  float* dtraw = (float*)(ws + 96731136);      // 9216*16 f32
  float* dt    = (float*)(ws + 97320960);      // 9216*16 f32
  float* Acum  = (float*)(ws + 97910784);      // 64*9*256 f32
  bf16t* xbc   = (bf16t*)(ws + 98500608);      // 9216*2176 bf16
  bf16t* x2bf  = (bf16t*)(ws + 98500608);      //   overlay after ssd_y: 8192*1024 bf16
  bf16t* hbuf  = (bf16t*)(ws + 115277824);     //   overlay: 8192*512 bf16
  bf16t* outw_bf = (bf16t*)(ws + 123666432);   //   overlay: 1024*2048 bf16
  bf16t* f1w_bf  = (bf16t*)(ws + 127860736);   //   overlay: 512*1024 bf16
  bf16t* f2w_bf  = (bf16t*)(ws + 128909312);   //   overlay: 1024*512 bf16
  float* cs    = (float*)(ws + 138608640);     // 576*8192 f32
  bf16t* inpw_bf = (bf16t*)(ws + 138608640);   //   overlay BEFORE chunk_states

  ln_cvt_kernel<<<B_ * T_ + 4352, 256, 0, stream>>>(
      localr, globalr, n1w, n1b, n2w, n2b, x, inpw, inpw_bf);

  gemm_wide<0, false, 1024><<<dim3(NPROJ_PAD / 128, (B_ * T_) / 256), 512, 0, stream>>>(
      x, inpw_bf, nullptr, z, xpre, dtraw, nullptr, nullptr, nullptr, NPROJ_PAD);

  conv_cumsum_kernel<<<CONVBLKS + B_ * NH * NCHUNK, 256, 0, stream>>>(
      xpre, convw, convb, xbc, dtraw, dtb, alog, dt, Acum);

  chunk_states_kernel<<<B_ * (NCHUNK - 1) * NH, 256, 0, stream>>>(xbc, dt, Acum, cs);

  state_pass_kernel<<<dim3(B_ * NH, 8), 256, 0, stream>>>(cs, Acum);

  ssd_y_kernel<<<dim3(B_ * (NCHUNK - 1) * NH, 2), 256, 0, stream>>>(
      xbc, dt, Acum, cs, dskp, Yb);

  gate_rms_cvt_kernel<<<B_ * L_ + 3072, 256, 0, stream>>>(
      z, ssdw, Yb, outw, f1w, f2w, outw_bf, f1w_bf, f2w_bf);

  gemm_wide<1, true, 2048><<<dim3(DM / 128, (B_ * L_) / 256), 512, 0, stream>>>(
      Yb, outw_bf, mfull, nullptr, nullptr, nullptr, nullptr, nullptr, nullptr, DM);

  res_ln3_kernel<<<B_ * L_, 256, 0, stream>>>(mfull, x, n3w, n3b, x2bf);

  gemm_mfma<2><<<dim3((DM / 2) / 128, (B_ * L_) / 128), 256, 0, stream>>>(
      x2bf, f1w_bf, f1b, nullptr, nullptr, hbuf, DM / 2, DM);

  gemm_wide<2, false, 512><<<dim3(DM / 128, (B_ * L_) / 256), 512, 0, stream>>>(
      hbuf, f2w_bf, nullptr, nullptr, nullptr, nullptr, f2b, x2bf, (float*)d_out, DM);
}

// Round 9
// 447.273 us; speedup vs baseline: 1.0269x; 1.0269x over previous
//
#include <hip/hip_runtime.h>
#include <math.h>

#define B_ 4
#define L_ 2048
#define G_ 256
#define T_ 2304          // G_ + L_
#define DM 1024
#define DINNER 2048
#define NH 16
#define HD 128
#define NSTATE 64
#define CONVD 2176       // DINNER + 2*NSTATE
#define DPROJ 4240       // 2*DINNER + 2*NSTATE + NH
#define NPROJ_PAD 4352   // DPROJ padded to 128
#define NCHUNK 9
#define CK 256
#define EPSV 1e-5f
#define CROWS 16         // conv rows per thread
#define CONVBLKS 612     // (B_*T_/CROWS)*272/256

typedef unsigned short bf16t;
using bf16x8 = __attribute__((ext_vector_type(8))) short;
using f32x4  = __attribute__((ext_vector_type(4))) float;

__device__ __forceinline__ float bf2f(bf16t u) {
  return __uint_as_float(((unsigned int)u) << 16);
}
__device__ __forceinline__ bf16t f2bf(float f) {
  unsigned int u = __float_as_uint(f);
  u += 0x7FFFu + ((u >> 16) & 1u);
  return (bf16t)(u >> 16);
}

__device__ __forceinline__ void g2lds16(const bf16t* g, short* l) {
  __builtin_amdgcn_global_load_lds(
      (const __attribute__((address_space(1))) unsigned int*)g,
      (__attribute__((address_space(3))) unsigned int*)l, 16, 0, 0);
}

// XCD-chunked bijective block swizzle (requires gridDim.x*gridDim.y % 8 == 0).
__device__ __forceinline__ int2 xcd_swz(int tiles_n) {
  int gx = gridDim.x, gy = gridDim.y;
  int id = blockIdx.y * gx + blockIdx.x;
  int cpx = (gx * gy) >> 3;
  int L = (id & 7) * cpx + (id >> 3);
  return make_int2(L % tiles_n, L / tiles_n);   // (nhat, mhat)
}

// ---------- block-wide reduction of two values (blockDim == 256) ----------
__device__ __forceinline__ float2 block_reduce2(float a, float b) {
  __shared__ float sa[4], sb[4];
  #pragma unroll
  for (int off = 32; off > 0; off >>= 1) {
    a += __shfl_down(a, off, 64);
    b += __shfl_down(b, off, 64);
  }
  int lane = threadIdx.x & 63, wid = threadIdx.x >> 6;
  if (lane == 0) { sa[wid] = a; sb[wid] = b; }
  __syncthreads();
  return make_float2(sa[0] + sa[1] + sa[2] + sa[3], sb[0] + sb[1] + sb[2] + sb[3]);
}

// ---------- LN1/LN2+concat (blocks 0..9215) fused with in_proj weight cvt ----------
__global__ __launch_bounds__(256) void ln_cvt_kernel(
    const float* __restrict__ localr, const float* __restrict__ globalr,
    const float* __restrict__ w1, const float* __restrict__ b1,
    const float* __restrict__ w2, const float* __restrict__ b2,
    bf16t* __restrict__ x, const float* __restrict__ inpw,
    bf16t* __restrict__ inpw_bf) {
  int blk = blockIdx.x;
  if (blk < B_ * T_) {
    int t = blk % T_, b = blk / T_;
    const float *src, *w, *bb;
    if (t < G_) { src = globalr + ((long)b * G_ + t) * DM;        w = w2; bb = b2; }
    else        { src = localr  + ((long)b * L_ + (t - G_)) * DM; w = w1; bb = b1; }
    int d = threadIdx.x * 4;
    float4 v = *(const float4*)&src[d];
    float s = v.x + v.y + v.z + v.w;
    float sq = v.x * v.x + v.y * v.y + v.z * v.z + v.w * v.w;
    float2 r2 = block_reduce2(s, sq);
    float mu = r2.x * (1.f / DM);
    float var = r2.y * (1.f / DM) - mu * mu;
    float rstd = rsqrtf(var + EPSV);
    float4 wv = *(const float4*)&w[d];
    float4 bv = *(const float4*)&bb[d];
    ushort4 o;
    o.x = f2bf((v.x - mu) * rstd * wv.x + bv.x);
    o.y = f2bf((v.y - mu) * rstd * wv.y + bv.y);
    o.z = f2bf((v.z - mu) * rstd * wv.z + bv.z);
    o.w = f2bf((v.w - mu) * rstd * wv.w + bv.w);
    *(ushort4*)&x[(long)blk * DM + d] = o;
  } else {
    long i = (long)(blk - B_ * T_) * 1024 + threadIdx.x * 4;
    const long nreal = (long)DPROJ * DM, ntot = (long)NPROJ_PAD * DM;
    if (i < ntot) {
      ushort4 o = {0, 0, 0, 0};
      if (i < nreal) {
        float4 v = *(const float4*)&inpw[i];
        o.x = f2bf(v.x); o.y = f2bf(v.y); o.z = f2bf(v.z); o.w = f2bf(v.w);
      }
      *(ushort4*)&inpw_bf[i] = o;
    }
  }
}

// ---------- wide GEMM: 256x128 tile, 8 waves (4M x 2N), BK=32, 2-phase/K-tile ----------
// 2 blocks/CU (72 KiB LDS). A: 3 slots [256][32]; B: 3 slots [128][32], both
// staged 2 tiles ahead into slot (t+2)%3 (last read >=2 barriers ago).
// Counted vmcnt(3)/tile. Swizzle key = (row>>1)&3 (NOT row&3): with 64B rows,
// bank-chunk = (4*row + g) mod 8, and only (row>>1)&3 cycles all 4 key values
// across same-parity rows -> 2-way (free) instead of 4-way conflicts.
// EPI 0: in_proj (z/xpre/dt routing); EPI 1: plain bf16 C (out_proj, OFFS remap);
// EPI 2: f32 C + bias + residual (ffn2 -> d_out).
template<int EPI, bool OFFS, int K>
__global__ __launch_bounds__(512, 4) void gemm_wide(
    const bf16t* __restrict__ A, const bf16t* __restrict__ W,
    bf16t* __restrict__ Cb, bf16t* __restrict__ z, bf16t* __restrict__ xpre,
    float* __restrict__ dtr, const float* __restrict__ bias,
    const bf16t* __restrict__ res, float* __restrict__ Cf, int N) {
  __shared__ short LDS8[36864];   // 72 KiB: A slots 0/8192/16384, B 24576+{0,4096,8192}
  int tid = threadIdx.x;
  int lane = tid & 63, w = tid >> 6;
  int wm = w >> 1, wn = w & 1;
  int l15 = lane & 15;
  int2 sz = xcd_swz(gridDim.x);
  int bn = sz.x * 128, bm = sz.y * 256;
  if (EPI == 0 && bn < DINNER && (bm % 2304) == 0) return;
  long bmA = OFFS ? ((long)(bm >> 11) * T_ + G_ + (bm & 2047)) : (long)bm;

  // staging: lane -> row_local = lane>>2, stored 16B-group = lane&3;
  // logical col group = (lane&3) ^ ((row>>1)&3) = (lane&3) ^ ((lane>>3)&3)
  int csub = ((lane & 3) ^ ((lane >> 3) & 3)) * 8;
  const bf16t* srcA = A + (bmA + w * 16 + (lane >> 2)) * (long)K + csub;
  const bf16t* srcW = W + (long)(bn + w * 16 + (lane >> 2)) * K + csub;
  int stageDst = w * 512 + lane * 8;     // shorts; wave covers 16 rows x 32 shorts

  // frag-read offset (shorts): row l15, stored group = (lane>>4) ^ ((l15>>1)&3)
  int off0 = l15 * 32 + (((lane >> 4) ^ ((l15 >> 1) & 3))) * 8;

  f32x4 acc[4][4] = {};
  bf16x8 af[4], bq[4];

#define STAGEA(gsrc, ldsoff) do { \
    g2lds16((gsrc), LDS8 + (ldsoff) + stageDst); \
    g2lds16((gsrc) + 128 * (long)K, LDS8 + (ldsoff) + stageDst + 4096); } while (0)
#define STAGEB(gsrc, ldsoff) g2lds16((gsrc), LDS8 + (ldsoff) + stageDst)

  // prologue: tiles 0 and 1; vmcnt(3) -> tile0's 3 loads landed (tile1's in flight)
  STAGEA(srcA, 0);
  STAGEB(srcW, 24576);
  STAGEA(srcA + 32, 8192);
  STAGEB(srcW + 32, 24576 + 4096);
  asm volatile("s_waitcnt vmcnt(3)" ::: "memory");
  __builtin_amdgcn_s_barrier();

  const int nt = K >> 5;
  for (int t = 0; t < nt; ++t) {
    const short* aB = LDS8 + (t % 3) * 8192 + wm * 2048;
    const short* bB = LDS8 + 24576 + (t % 3) * 4096 + wn * 2048;
    int nsA = ((t + 2) % 3) * 8192;
    int nsB = 24576 + ((t + 2) % 3) * 4096;

    // ---- phase 1: read A(mi0-3)+B(ni0-1); MFMA half; stage A(t+2) ----
    #pragma unroll
    for (int mi = 0; mi < 4; mi++) af[mi] = *(const bf16x8*)&aB[mi * 512 + off0];
    #pragma unroll
    for (int ni = 0; ni < 2; ni++) bq[ni] = *(const bf16x8*)&bB[ni * 512 + off0];
    if (t + 2 < nt) STAGEA(srcA + (t + 2) * 32, nsA);
    __builtin_amdgcn_s_barrier();
    __builtin_amdgcn_s_setprio(1);
    #pragma unroll
    for (int mi = 0; mi < 4; mi++)
      #pragma unroll
      for (int ni = 0; ni < 2; ni++)
        acc[mi][ni] = __builtin_amdgcn_mfma_f32_16x16x32_bf16(af[mi], bq[ni], acc[mi][ni], 0, 0, 0);
    __builtin_amdgcn_s_setprio(0);
    __builtin_amdgcn_s_barrier();

    // ---- phase 2: read B(ni2-3); MFMA half; stage B(t+2); counted vmcnt ----
    #pragma unroll
    for (int ni = 2; ni < 4; ni++) bq[ni] = *(const bf16x8*)&bB[ni * 512 + off0];
    if (t + 2 < nt) STAGEB(srcW + (t + 2) * 32, nsB);
    __builtin_amdgcn_s_barrier();
    __builtin_amdgcn_s_setprio(1);
    #pragma unroll
    for (int mi = 0; mi < 4; mi++)
      #pragma unroll
      for (int ni = 2; ni < 4; ni++)
        acc[mi][ni] = __builtin_amdgcn_mfma_f32_16x16x32_bf16(af[mi], bq[ni], acc[mi][ni], 0, 0, 0);
    __builtin_amdgcn_s_setprio(0);
    if (t + 2 < nt)      asm volatile("s_waitcnt vmcnt(3)" ::: "memory");
    else if (t + 1 < nt) asm volatile("s_waitcnt vmcnt(0)" ::: "memory");
    __builtin_amdgcn_s_barrier();
  }
#undef STAGEA
#undef STAGEB

  // ---- epilogue ----
  if (EPI == 0 && bn == 4224) {
    if (wn == 0) {
      #pragma unroll
      for (int mi = 0; mi < 4; mi++)
        #pragma unroll
        for (int r = 0; r < 4; r++) {
          int row = bm + wm * 64 + mi * 16 + (lane >> 4) * 4 + r;
          dtr[(long)row * NH + l15] = acc[mi][0][r];
        }
    }
    return;
  }

  if (EPI == 2) {
    // f32 + bias + residual (ffn2): 4 passes of 64 rows (fits LDS)
    float* Cs32 = (float*)LDS8;               // [64][136] f32 = 34816 B
    #pragma unroll
    for (int pass = 0; pass < 4; pass++) {
      __syncthreads();
      if (wm == pass) {
        #pragma unroll
        for (int mi = 0; mi < 4; mi++)
          #pragma unroll
          for (int ni = 0; ni < 4; ni++)
            #pragma unroll
            for (int r = 0; r < 4; r++)
              Cs32[(mi * 16 + (lane >> 4) * 4 + r) * 136 + wn * 64 + ni * 16 + l15] =
                  acc[mi][ni][r];
      }
      __syncthreads();
      #pragma unroll
      for (int q = 0; q < 2; q++) {
        int idx = q * 512 + tid;             // 64 rows x 16 groups of 8 f32
        int row = idx >> 4, cg = (idx & 15) * 8;
        long grow = bm + pass * 64 + row; int gcol = bn + cg;
        float4 v0 = *(float4*)&Cs32[row * 136 + cg];
        float4 v1 = *(float4*)&Cs32[row * 136 + cg + 4];
        float4 b0 = *(const float4*)&bias[gcol];
        float4 b1 = *(const float4*)&bias[gcol + 4];
        bf16x8 rv = *(const bf16x8*)&res[grow * (long)N + gcol];
        v0.x += b0.x + bf2f((bf16t)rv[0]); v0.y += b0.y + bf2f((bf16t)rv[1]);
        v0.z += b0.z + bf2f((bf16t)rv[2]); v0.w += b0.w + bf2f((bf16t)rv[3]);
        v1.x += b1.x + bf2f((bf16t)rv[4]); v1.y += b1.y + bf2f((bf16t)rv[5]);
        v1.z += b1.z + bf2f((bf16t)rv[6]); v1.w += b1.w + bf2f((bf16t)rv[7]);
        *(float4*)&Cf[grow * (long)N + gcol] = v0;
        *(float4*)&Cf[grow * (long)N + gcol + 4] = v1;
      }
    }
    return;
  }

  // bf16 C via LDS roundtrip: 2 passes of 128 rows ([128][136] bf16 = 34816 B)
  bf16t* Cs = (bf16t*)LDS8;
  #pragma unroll
  for (int pass = 0; pass < 2; pass++) {
    __syncthreads();
    if ((wm >> 1) == pass) {
      #pragma unroll
      for (int mi = 0; mi < 4; mi++)
        #pragma unroll
        for (int ni = 0; ni < 4; ni++)
          #pragma unroll
          for (int r = 0; r < 4; r++)
            Cs[((wm & 1) * 64 + mi * 16 + (lane >> 4) * 4 + r) * 136 + wn * 64 + ni * 16 + l15] =
                f2bf(acc[mi][ni][r]);
    }
    __syncthreads();
    #pragma unroll
    for (int q = 0; q < 4; q++) {
      int idx = q * 512 + tid;
      int row = idx >> 4, cg = idx & 15;
      int gcol = bn + cg * 8;
      long grow = bm + pass * 128 + row;
      bf16x8 v = *(bf16x8*)&Cs[row * 136 + cg * 8];
      if (EPI == 0) {
        if (gcol < DINNER) *(bf16x8*)&z[grow * DINNER + gcol] = v;
        else               *(bf16x8*)&xpre[grow * CONVD + (gcol - DINNER)] = v;
      } else {
        *(bf16x8*)&Cb[grow * (long)N + gcol] = v;
      }
    }
  }
}

// ---------- MFMA bf16 GEMM 128x128 (ffn1: gelu(v+bias)) ----------
template<int EPI>
__global__ __launch_bounds__(256) void gemm_mfma(
    const bf16t* __restrict__ A, const bf16t* __restrict__ W,
    const float* __restrict__ bias, const bf16t* __restrict__ res,
    float* __restrict__ Cf, bf16t* __restrict__ Cb,
    int N, int K) {
  __shared__ __align__(16) short LDS[128 * 136];
  short* As = LDS;              // [128][32]
  short* Ws = LDS + 128 * 32;   // [128][32]
  int tid = threadIdx.x;
  int lane = tid & 63, w = tid >> 6;
  int wr = w >> 1, wc = w & 1;
  int2 sz = xcd_swz(gridDim.x);
  int bn = sz.x * 128, bm = sz.y * 128;

  int r1 = tid >> 2,         s1 = (((tid & 3) ^ ((r1 >> 1) & 3))) * 8;
  int r2 = (tid + 256) >> 2, s2 = (((tid & 3) ^ ((r2 >> 1) & 3))) * 8;
  const bf16t* gA1 = A + (long)(bm + r1) * K + s1;
  const bf16t* gA2 = A + (long)(bm + r2) * K + s2;
  const bf16t* gW1 = W + (long)(bn + r1) * K + s1;
  const bf16t* gW2 = W + (long)(bn + r2) * K + s2;
  short* lA1 = As + tid * 8;
  short* lA2 = As + (tid + 256) * 8;
  short* lW1 = Ws + tid * 8;
  short* lW2 = Ws + (tid + 256) * 8;

  int arow = wr * 64 + (lane & 15);
  int brow = wc * 64 + (lane & 15);
  int koff = (((lane >> 4) ^ (((lane & 15) >> 1) & 3))) * 8;

  f32x4 acc[4][4] = {};
  for (int k0 = 0; k0 < K; k0 += 32) {
    g2lds16(gA1 + k0, lA1);
    g2lds16(gA2 + k0, lA2);
    g2lds16(gW1 + k0, lW1);
    g2lds16(gW2 + k0, lW2);
    __syncthreads();
    bf16x8 af[4], bf[4];
    #pragma unroll
    for (int mi = 0; mi < 4; mi++) af[mi] = *(bf16x8*)&As[(arow + mi * 16) * 32 + koff];
    #pragma unroll
    for (int ni = 0; ni < 4; ni++) bf[ni] = *(bf16x8*)&Ws[(brow + ni * 16) * 32 + koff];
    #pragma unroll
    for (int mi = 0; mi < 4; mi++)
      #pragma unroll
      for (int ni = 0; ni < 4; ni++)
        acc[mi][ni] = __builtin_amdgcn_mfma_f32_16x16x32_bf16(af[mi], bf[ni], acc[mi][ni], 0, 0, 0);
    __syncthreads();
  }

  int rb = wr * 64 + (lane >> 4) * 4;
  int cb = wc * 64 + (lane & 15);

  __syncthreads();
  bf16t* Cs = (bf16t*)LDS;                     // [128][136]
  #pragma unroll
  for (int mi = 0; mi < 4; mi++)
    #pragma unroll
    for (int ni = 0; ni < 4; ni++)
      #pragma unroll
      for (int r = 0; r < 4; r++) {
        float v = acc[mi][ni][r];
        if (EPI == 2) {
          v += bias[bn + cb + ni * 16];
          v = 0.5f * v * (1.f + erff(v * 0.70710678118f));
        }
        Cs[(rb + mi * 16 + r) * 136 + cb + ni * 16] = f2bf(v);
      }
  __syncthreads();
  #pragma unroll
  for (int pass = 0; pass < 8; pass++) {
    int row = pass * 16 + (tid >> 4);
    int col = (tid & 15) * 8;
    bf16x8 vv = *(bf16x8*)&Cs[row * 136 + col];
    long grow = bm + row; int gcol = bn + col;
    *(bf16x8*)&Cb[grow * N + gcol] = vv;
  }
}

// ---------- merged: causal conv(4)+bias+silu  AND  dt softplus + chunk cumsum ----------
__global__ __launch_bounds__(256) void conv_cumsum_kernel(
    const bf16t* __restrict__ xpre, const float* __restrict__ cw,
    const float* __restrict__ cb, bf16t* __restrict__ out,
    const float* __restrict__ dtraw, const float* __restrict__ dt_bias,
    const float* __restrict__ A_log, float* __restrict__ dt,
    float* __restrict__ Acum) {
  if (blockIdx.x < CONVBLKS) {
    int gt = blockIdx.x * 256 + threadIdx.x;    // < 576*272
    int cg = gt % 272; int rt = gt / 272;
    int c0 = cg * 8;
    long r0 = (long)rt * CROWS;
    int t0 = (int)(r0 % T_);

    float wreg[4][8];
    #pragma unroll
    for (int j = 0; j < 8; j++) {
      float4 wa = *(const float4*)&cw[(c0 + j) * 4];
      wreg[0][j] = wa.x; wreg[1][j] = wa.y; wreg[2][j] = wa.z; wreg[3][j] = wa.w;
    }
    float4 cb0 = *(const float4*)&cb[c0];
    float4 cb1 = *(const float4*)&cb[c0 + 4];
    float bias[8] = {cb0.x, cb0.y, cb0.z, cb0.w, cb1.x, cb1.y, cb1.z, cb1.w};

    bf16x8 win[4];
    #pragma unroll
    for (int i = 0; i < 3; i++) {
      if (t0 - 3 + i >= 0) win[i] = *(const bf16x8*)&xpre[(r0 - 3 + i) * CONVD + c0];
      else                 win[i] = bf16x8{0,0,0,0,0,0,0,0};
    }

    #pragma unroll
    for (int k = 0; k < CROWS; k++) {
      win[3] = *(const bf16x8*)&xpre[(r0 + k) * CONVD + c0];
      float acc[8];
      #pragma unroll
      for (int j = 0; j < 8; j++) acc[j] = bias[j];
      #pragma unroll
      for (int i = 0; i < 4; i++)
        #pragma unroll
        for (int j = 0; j < 8; j++)
          acc[j] += bf2f((bf16t)win[i][j]) * wreg[i][j];
      bf16x8 o;
      #pragma unroll
      for (int j = 0; j < 8; j++) {
        float s = acc[j] / (1.f + __expf(-acc[j]));
        o[j] = (short)f2bf(s);
      }
      *(bf16x8*)&out[(r0 + k) * CONVD + c0] = o;
      win[0] = win[1]; win[1] = win[2]; win[2] = win[3];
    }
  } else {
    int bid = blockIdx.x - CONVBLKS;      // (b*NH+h)*NCHUNK + c
    int c = bid % NCHUNK; int hh = bid / NCHUNK;
    int h = hh % NH; int b = hh / NH;
    int k = threadIdx.x;
    float a = -__expf(A_log[h]);
    long t = (long)b * T_ + c * CK + k;
    float v0 = dtraw[t * NH + h] + dt_bias[h];
    float dtv = (v0 > 20.f) ? v0 : log1pf(__expf(v0));
    dt[t * NH + h] = dtv;
    float v = dtv * a;
    __shared__ float buf[2][CK];
    int cur = 0;
    buf[0][k] = v; __syncthreads();
    for (int off = 1; off < CK; off <<= 1) {
      float tv = buf[cur][k];
      if (k >= off) tv += buf[cur][k - off];
      buf[1 - cur][k] = tv; cur ^= 1; __syncthreads();
    }
    Acum[(long)bid * CK + k] = buf[cur][k];
  }
}

// ---------- per-chunk states via MFMA (chunks 0..7 only; chunk 8 unused) ----------
__global__ __launch_bounds__(256) void chunk_states_kernel(
    const bf16t* __restrict__ xbc, const float* __restrict__ dt,
    const float* __restrict__ Acum, float* __restrict__ cs) {
  int bid = blockIdx.x;                 // 512
  int h = bid & 15; int bc = bid >> 4;
  int c = bc & 7; int b = bc >> 3;
  int tid = threadIdx.x;
  int lane = tid & 63, w = tid >> 6;
  long tch = (long)b * T_ + c * CK;
  int acb = ((b * NH + h) * NCHUNK + c) * CK;
  float Alast = Acum[acb + CK - 1];

  __shared__ bf16t Xt[128][72];
  __shared__ bf16t Bt[64][72];
  __shared__ float wkv[256];
  // preload full chunk decay*dt weights once (replaces per-kb barrier+gather)
  wkv[tid] = __expf(Alast - Acum[acb + tid]) * dt[(tch + tid) * NH + h];

  f32x4 acc[8] = {};
  for (int kb = 0; kb < 4; kb++) {
    int s0 = kb * 64;
    __syncthreads();
    // Xt: 4-col packed ds_write_b64 transpose staging
    for (int e = tid; e < 16 * 32; e += 256) {
      int s4 = (e & 15) * 4, p4 = e >> 4;
      const bf16t* base = &xbc[(tch + s0 + s4) * CONVD + h * HD + p4 * 4];
      ushort4 u0 = *(const ushort4*)(base);
      ushort4 u1 = *(const ushort4*)(base + CONVD);
      ushort4 u2 = *(const ushort4*)(base + 2 * CONVD);
      ushort4 u3 = *(const ushort4*)(base + 3 * CONVD);
      float w0 = wkv[s0 + s4], w1 = wkv[s0 + s4 + 1];
      float w2 = wkv[s0 + s4 + 2], w3 = wkv[s0 + s4 + 3];
      ushort4 pk;
      pk.x = f2bf(bf2f(u0.x) * w0); pk.y = f2bf(bf2f(u1.x) * w1);
      pk.z = f2bf(bf2f(u2.x) * w2); pk.w = f2bf(bf2f(u3.x) * w3);
      *(ushort4*)&Xt[p4 * 4 + 0][s4] = pk;
      pk.x = f2bf(bf2f(u0.y) * w0); pk.y = f2bf(bf2f(u1.y) * w1);
      pk.z = f2bf(bf2f(u2.y) * w2); pk.w = f2bf(bf2f(u3.y) * w3);
      *(ushort4*)&Xt[p4 * 4 + 1][s4] = pk;
      pk.x = f2bf(bf2f(u0.z) * w0); pk.y = f2bf(bf2f(u1.z) * w1);
      pk.z = f2bf(bf2f(u2.z) * w2); pk.w = f2bf(bf2f(u3.z) * w3);
      *(ushort4*)&Xt[p4 * 4 + 2][s4] = pk;
      pk.x = f2bf(bf2f(u0.w) * w0); pk.y = f2bf(bf2f(u1.w) * w1);
      pk.z = f2bf(bf2f(u2.w) * w2); pk.w = f2bf(bf2f(u3.w) * w3);
      *(ushort4*)&Xt[p4 * 4 + 3][s4] = pk;
    }
    // Bt: same packing, no scale
    for (int e = tid; e < 16 * 16; e += 256) {
      int s4 = (e & 15) * 4, n4 = e >> 4;
      const bf16t* base = &xbc[(tch + s0 + s4) * CONVD + DINNER + n4 * 4];
      ushort4 u0 = *(const ushort4*)(base);
      ushort4 u1 = *(const ushort4*)(base + CONVD);
      ushort4 u2 = *(const ushort4*)(base + 2 * CONVD);
      ushort4 u3 = *(const ushort4*)(base + 3 * CONVD);
      ushort4 pk;
      pk.x = u0.x; pk.y = u1.x; pk.z = u2.x; pk.w = u3.x;
      *(ushort4*)&Bt[n4 * 4 + 0][s4] = pk;
      pk.x = u0.y; pk.y = u1.y; pk.z = u2.y; pk.w = u3.y;
      *(ushort4*)&Bt[n4 * 4 + 1][s4] = pk;
      pk.x = u0.z; pk.y = u1.z; pk.z = u2.z; pk.w = u3.z;
      *(ushort4*)&Bt[n4 * 4 + 2][s4] = pk;
      pk.x = u0.w; pk.y = u1.w; pk.z = u2.w; pk.w = u3.w;
      *(ushort4*)&Bt[n4 * 4 + 3][s4] = pk;
    }
    __syncthreads();
    #pragma unroll
    for (int ks = 0; ks < 2; ks++) {
      int koff = (lane >> 4) * 8 + ks * 32;
      bf16x8 bfr = *(bf16x8*)&Bt[w * 16 + (lane & 15)][koff];
      #pragma unroll
      for (int mi = 0; mi < 8; mi++) {
        bf16x8 af = *(bf16x8*)&Xt[mi * 16 + (lane & 15)][koff];
        acc[mi] = __builtin_amdgcn_mfma_f32_16x16x32_bf16(af, bfr, acc[mi], 0, 0, 0);
      }
    }
  }
  int cbid = (b * NCHUNK + c) * NH + h;
  float* out = cs + (long)cbid * HD * NSTATE;
  int n = w * 16 + (lane & 15);
  #pragma unroll
  for (int mi = 0; mi < 8; mi++) {
    #pragma unroll
    for (int r = 0; r < 4; r++) {
      int p = mi * 16 + (lane >> 4) * 4 + r;
      out[p * NSTATE + n] = acc[mi][r];
    }
  }
}

// ---------- sequential inter-chunk recurrence, IN PLACE ----------
__global__ __launch_bounds__(256) void state_pass_kernel(
    float* __restrict__ cs, const float* __restrict__ Acum) {
  int bh = blockIdx.x;                  // b*NH + h
  int b = bh / NH, h = bh % NH;
  int e0 = blockIdx.y * 1024 + threadIdx.x;
  for (int q = 0; q < 4; q++) {
    int e = e0 + q * 256;
    float s = 0.f;
    for (int c = 0; c < NCHUNK; c++) {
      long idx = ((long)(b * NCHUNK + c) * NH + h) * (HD * NSTATE) + e;
      if (c < NCHUNK - 1) {
        float tmp = cs[idx];
        cs[idx] = s;
        float g = __expf(Acum[((b * NH + h) * NCHUNK + c) * CK + CK - 1]);
        s = s * g + tmp;
      } else {
        cs[idx] = s;
      }
    }
  }
}

// ---------- SSD Y via MFMA (chunks 1..8; chunk 0's Y is discarded downstream) ----------
__global__ __launch_bounds__(256) void ssd_y_kernel(
    const bf16t* __restrict__ xbc, const float* __restrict__ dt,
    const float* __restrict__ Acum, const float* __restrict__ sin_,
    const float* __restrict__ Dskip, bf16t* __restrict__ Y) {
  int bid = blockIdx.x;                 // 512
  int h = bid & 15; int bc = bid >> 4;
  int c = 1 + (bc & 7); int b = bc >> 3;
  int rt = blockIdx.y;
  int tid = threadIdx.x;
  int lane = tid & 63, w = tid >> 6;
  int wr = w >> 1, wc = w & 1;
  long tch = (long)b * T_ + c * CK;
  long tbase = tch + rt * 128;
  int acb = ((b * NH + h) * NCHUNK + c) * CK;

  __shared__ bf16t Cs[128][72];
  __shared__ bf16t Bs[64][72];
  __shared__ __align__(16) bf16t XtSm[2][128][72];   // Xt | Sm; reused as f32 pad for Y-write
  bf16t (*Xt)[72] = XtSm[0];
  bf16t (*Sm)[72] = XtSm[1];
  __shared__ float Acv[256];
  __shared__ float dtv[256];

  for (int e = tid; e < 128 * 8; e += 256) {
    int row = e >> 3, seg = (e & 7) * 8;
    *(bf16x8*)&Cs[row][seg] =
        *(const bf16x8*)&xbc[(tbase + row) * CONVD + DINNER + NSTATE + seg];
  }
  // preload full chunk Acum and dt once (replaces per-sb barrier+gather)
  Acv[tid] = Acum[acb + tid];
  dtv[tid] = dt[(tch + tid) * NH + h];
  const float* Ak = Acv + rt * 128;

  f32x4 acc[4][4] = {};
  int nsb = 2 * (rt + 1);
  for (int sb = 0; sb < nsb; sb++) {
    int s0 = sb * 64;
    __syncthreads();
    for (int e = tid; e < 64 * 8; e += 256) {
      int row = e >> 3, seg = (e & 7) * 8;
      *(bf16x8*)&Bs[row][seg] =
          *(const bf16x8*)&xbc[(tch + s0 + row) * CONVD + DINNER + seg];
    }
    // Xt: 4-col packed ds_write_b64 transpose staging (scaled by dt)
    for (int e = tid; e < 16 * 32; e += 256) {
      int s4 = (e & 15) * 4, p4 = e >> 4;
      const bf16t* base = &xbc[(tch + s0 + s4) * CONVD + h * HD + p4 * 4];
      ushort4 u0 = *(const ushort4*)(base);
      ushort4 u1 = *(const ushort4*)(base + CONVD);
      ushort4 u2 = *(const ushort4*)(base + 2 * CONVD);
      ushort4 u3 = *(const ushort4*)(base + 3 * CONVD);
      float d0 = dtv[s0 + s4], d1 = dtv[s0 + s4 + 1];
      float d2 = dtv[s0 + s4 + 2], d3 = dtv[s0 + s4 + 3];
      ushort4 pk;
      pk.x = f2bf(bf2f(u0.x) * d0); pk.y = f2bf(bf2f(u1.x) * d1);
      pk.z = f2bf(bf2f(u2.x) * d2); pk.w = f2bf(bf2f(u3.x) * d3);
      *(ushort4*)&Xt[p4 * 4 + 0][s4] = pk;
      pk.x = f2bf(bf2f(u0.y) * d0); pk.y = f2bf(bf2f(u1.y) * d1);
      pk.z = f2bf(bf2f(u2.y) * d2); pk.w = f2bf(bf2f(u3.y) * d3);
      *(ushort4*)&Xt[p4 * 4 + 1][s4] = pk;
      pk.x = f2bf(bf2f(u0.z) * d0); pk.y = f2bf(bf2f(u1.z) * d1);
      pk.z = f2bf(bf2f(u2.z) * d2); pk.w = f2bf(bf2f(u3.z) * d3);
      *(ushort4*)&Xt[p4 * 4 + 2][s4] = pk;
      pk.x = f2bf(bf2f(u0.w) * d0); pk.y = f2bf(bf2f(u1.w) * d1);
      pk.z = f2bf(bf2f(u2.w) * d2); pk.w = f2bf(bf2f(u3.w) * d3);
      *(ushort4*)&Xt[p4 * 4 + 3][s4] = pk;
    }
    __syncthreads();
    {
      f32x4 sacc[2][4] = {};
      int rw0 = w * 32;
      #pragma unroll
      for (int ks = 0; ks < 2; ks++) {
        int koff = (lane >> 4) * 8 + ks * 32;
        bf16x8 a0 = *(bf16x8*)&Cs[rw0 + (lane & 15)][koff];
        bf16x8 a1 = *(bf16x8*)&Cs[rw0 + 16 + (lane & 15)][koff];
        #pragma unroll
        for (int ni = 0; ni < 4; ni++) {
          bf16x8 bfr = *(bf16x8*)&Bs[ni * 16 + (lane & 15)][koff];
          sacc[0][ni] = __builtin_amdgcn_mfma_f32_16x16x32_bf16(a0, bfr, sacc[0][ni], 0, 0, 0);
          sacc[1][ni] = __builtin_amdgcn_mfma_f32_16x16x32_bf16(a1, bfr, sacc[1][ni], 0, 0, 0);
        }
      }
      #pragma unroll
      for (int mi = 0; mi < 2; mi++) {
        #pragma unroll
        for (int ni = 0; ni < 4; ni++) {
          #pragma unroll
          for (int r = 0; r < 4; r++) {
            int row = rw0 + mi * 16 + (lane >> 4) * 4 + r;
            int scol = ni * 16 + (lane & 15);
            int kglob = rt * 128 + row;
            int sglob = s0 + scol;
            float val = 0.f;
            if (sglob <= kglob) val = sacc[mi][ni][r] * __expf(Ak[row] - Acv[s0 + scol]);
            Sm[row][scol] = f2bf(val);
          }
        }
      }
    }
    __syncthreads();
    #pragma unroll
    for (int ks = 0; ks < 2; ks++) {
      int koff = (lane >> 4) * 8 + ks * 32;
      bf16x8 af[4], bfr[4];
      #pragma unroll
      for (int mi = 0; mi < 4; mi++) af[mi] = *(bf16x8*)&Sm[wr * 64 + mi * 16 + (lane & 15)][koff];
      #pragma unroll
      for (int ni = 0; ni < 4; ni++) bfr[ni] = *(bf16x8*)&Xt[wc * 64 + ni * 16 + (lane & 15)][koff];
      #pragma unroll
      for (int mi = 0; mi < 4; mi++)
        #pragma unroll
        for (int ni = 0; ni < 4; ni++)
          acc[mi][ni] = __builtin_amdgcn_mfma_f32_16x16x32_bf16(af[mi], bfr[ni], acc[mi][ni], 0, 0, 0);
    }
  }

  float ekr[16];
  #pragma unroll
  for (int mi = 0; mi < 4; mi++)
    #pragma unroll
    for (int r = 0; r < 4; r++)
      ekr[mi * 4 + r] = __expf(Ak[wr * 64 + mi * 16 + (lane >> 4) * 4 + r]);

  int cbid = (b * NCHUNK + c) * NH + h;
  const float* sinb = sin_ + (long)cbid * HD * NSTATE;
  #pragma unroll
  for (int ni = 0; ni < 4; ni++) {
    f32x4 offacc[4] = {};
    int p = wc * 64 + ni * 16 + (lane & 15);
    #pragma unroll
    for (int ks = 0; ks < 2; ks++) {
      int koff = (lane >> 4) * 8 + ks * 32;
      const float* srow = sinb + p * NSTATE + koff;
      float4 sa = *(const float4*)srow;
      float4 sbv = *(const float4*)(srow + 4);
      bf16x8 bfr;
      bfr[0] = (short)f2bf(sa.x);  bfr[1] = (short)f2bf(sa.y);
      bfr[2] = (short)f2bf(sa.z);  bfr[3] = (short)f2bf(sa.w);
      bfr[4] = (short)f2bf(sbv.x); bfr[5] = (short)f2bf(sbv.y);
      bfr[6] = (short)f2bf(sbv.z); bfr[7] = (short)f2bf(sbv.w);
      #pragma unroll
      for (int mi = 0; mi < 4; mi++) {
        bf16x8 af = *(bf16x8*)&Cs[wr * 64 + mi * 16 + (lane & 15)][koff];
        offacc[mi] = __builtin_amdgcn_mfma_f32_16x16x32_bf16(af, bfr, offacc[mi], 0, 0, 0);
      }
    }
    #pragma unroll
    for (int mi = 0; mi < 4; mi++)
      #pragma unroll
      for (int r = 0; r < 4; r++)
        acc[mi][ni][r] += ekr[mi * 4 + r] * offacc[mi][r];
  }

  // ---- vectorized Y write: acc (f32) through LDS (dead Xt+Sm), bf16x8 IO ----
  float dsk = Dskip[h];
  float* Sf = (float*)&XtSm[0][0][0];          // [64][130] f32 (33280 B <= 36864)
  #pragma unroll
  for (int rh = 0; rh < 2; rh++) {
    __syncthreads();
    if (wr == rh) {
      #pragma unroll
      for (int mi = 0; mi < 4; mi++)
        #pragma unroll
        for (int ni = 0; ni < 4; ni++)
          #pragma unroll
          for (int r = 0; r < 4; r++)
            Sf[(mi * 16 + (lane >> 4) * 4 + r) * 130 + wc * 64 + ni * 16 + (lane & 15)] =
                acc[mi][ni][r];
    }
    __syncthreads();
    #pragma unroll
    for (int g = 0; g < 4; g++) {
      int idx = g * 256 + tid;                 // 64 rows x 16 col-groups
      int row = idx >> 4, cg = (idx & 15) * 8;
      long t = tbase + rh * 64 + row;
      bf16x8 xv = *(const bf16x8*)&xbc[t * CONVD + h * HD + cg];
      bf16x8 o;
      #pragma unroll
      for (int j = 0; j < 8; j++)
        o[j] = (short)f2bf(Sf[row * 130 + cg + j] + dsk * bf2f((bf16t)xv[j]));
      *(bf16x8*)&Y[t * DINNER + h * HD + cg] = o;
    }
  }
}

// ---------- gate+RMSNorm (local rows only) fused with late weight cvt ----------
__global__ __launch_bounds__(256) void gate_rms_cvt_kernel(
    const bf16t* __restrict__ z, const float* __restrict__ nw,
    bf16t* __restrict__ Y,
    const float* __restrict__ outw, const float* __restrict__ f1w,
    const float* __restrict__ f2w, bf16t* __restrict__ o_out,
    bf16t* __restrict__ o_f1, bf16t* __restrict__ o_f2) {
  int blk = blockIdx.x;
  if (blk < B_ * L_) {
    long r = (long)(blk >> 11) * T_ + G_ + (blk & 2047);
    const bf16t* zrow = z + r * DINNER;
    bf16t* yrow = Y + r * DINNER;
    int tid = threadIdx.x;
    int d = tid * 8;
    bf16x8 zu = *(const bf16x8*)&zrow[d];
    bf16x8 yu = *(const bf16x8*)&yrow[d];
    float v[8]; float sq = 0.f;
    #pragma unroll
    for (int j = 0; j < 8; j++) {
      float z0 = bf2f((bf16t)zu[j]);
      float y0 = bf2f((bf16t)yu[j]) * (z0 / (1.f + __expf(-z0)));
      v[j] = y0; sq += y0 * y0;
    }
    float2 r2 = block_reduce2(sq, 0.f);
    float rms = rsqrtf(r2.x * (1.f / DINNER) + EPSV);
    float4 nw0 = *(const float4*)&nw[d];
    float4 nw1 = *(const float4*)&nw[d + 4];
    float nn[8] = {nw0.x, nw0.y, nw0.z, nw0.w, nw1.x, nw1.y, nw1.z, nw1.w};
    bf16x8 o;
    #pragma unroll
    for (int j = 0; j < 8; j++) o[j] = (short)f2bf(v[j] * rms * nn[j]);
    *(bf16x8*)&yrow[d] = o;
  } else {
    long i = (long)(blk - B_ * L_) * 1024 + threadIdx.x * 4;
    const long n1 = (long)DM * DINNER;          // 2097152
    const long n2 = (long)(DM / 2) * DM;        // 524288
    const float* src; bf16t* dst; long off;
    if (i < n1) { src = outw; dst = o_out; off = i; }
    else if (i < n1 + n2) { src = f1w; dst = o_f1; off = i - n1; }
    else { src = f2w; dst = o_f2; off = i - n1 - n2; }
    float4 v = *(const float4*)&src[off];
    ushort4 o;
    o.x = f2bf(v.x); o.y = f2bf(v.y); o.z = f2bf(v.z); o.w = f2bf(v.w);
    *(ushort4*)&dst[off] = o;
  }
}

// ---------- residual add + LayerNorm3 -> bf16 (mfull compact [8192][1024]) ----------
__global__ __launch_bounds__(256) void res_ln3_kernel(
    const bf16t* __restrict__ mfull, const bf16t* __restrict__ x,
    const float* __restrict__ w3, const float* __restrict__ b3,
    bf16t* __restrict__ x2) {
  int rl = blockIdx.x;                  // b*L_ + tl
  int tl = rl & 2047, b = rl >> 11;
  long rt = (long)b * T_ + G_ + tl;
  const bf16t* m = mfull + (long)rl * DM;
  const bf16t* xr = x + rt * DM;
  int tid = threadIdx.x;
  int d = tid * 4;
  ushort4 mu4 = *(const ushort4*)&m[d];
  ushort4 xu4 = *(const ushort4*)&xr[d];
  float v[4];
  v[0] = bf2f(mu4.x) + bf2f(xu4.x);
  v[1] = bf2f(mu4.y) + bf2f(xu4.y);
  v[2] = bf2f(mu4.z) + bf2f(xu4.z);
  v[3] = bf2f(mu4.w) + bf2f(xu4.w);
  float s = v[0] + v[1] + v[2] + v[3];
  float sq = v[0]*v[0] + v[1]*v[1] + v[2]*v[2] + v[3]*v[3];
  float2 r2 = block_reduce2(s, sq);
  float mu = r2.x * (1.f / DM);
  float var = r2.y * (1.f / DM) - mu * mu;
  float rstd = rsqrtf(var + EPSV);
  float4 w4 = *(const float4*)&w3[d];
  float4 b4 = *(const float4*)&b3[d];
  ushort4 o;
  o.x = f2bf((v[0] - mu) * rstd * w4.x + b4.x);
  o.y = f2bf((v[1] - mu) * rstd * w4.y + b4.y);
  o.z = f2bf((v[2] - mu) * rstd * w4.z + b4.z);
  o.w = f2bf((v[3] - mu) * rstd * w4.w + b4.w);
  *(ushort4*)&x2[(long)rl * DM + d] = o;
}

extern "C" void kernel_launch(void* const* d_in, const int* in_sizes, int n_in,
                              void* d_out, int out_size, void* d_ws, size_t ws_size,
                              hipStream_t stream) {
  const float* localr = (const float*)d_in[0];
  const float* globalr= (const float*)d_in[1];
  const float* n1w = (const float*)d_in[2];
  const float* n1b = (const float*)d_in[3];
  const float* n2w = (const float*)d_in[4];
  const float* n2b = (const float*)d_in[5];
  const float* n3w = (const float*)d_in[6];
  const float* n3b = (const float*)d_in[7];
  const float* inpw= (const float*)d_in[8];
  const float* convw=(const float*)d_in[9];
  const float* convb=(const float*)d_in[10];
  const float* dtb = (const float*)d_in[11];
  const float* alog= (const float*)d_in[12];
  const float* dskp= (const float*)d_in[13];
  const float* ssdw= (const float*)d_in[14];
  const float* outw= (const float*)d_in[15];
  const float* f1w = (const float*)d_in[16];
  const float* f1b = (const float*)d_in[17];
  const float* f2w = (const float*)d_in[18];
  const float* f2b = (const float*)d_in[19];

  // ---- workspace layout (byte offsets); peak ~150 MB ----
  char* ws = (char*)d_ws;
  bf16t* x     = (bf16t*)(ws + 0);             // 9216*1024 bf16
  bf16t* z     = (bf16t*)(ws + 18874368);      // 9216*2048 bf16
  bf16t* mfull = (bf16t*)(ws + 18874368);      //   overlay: 8192*1024 bf16 compact
  bf16t* xpre  = (bf16t*)(ws + 56623104);      // 9216*2176 bf16
  bf16t* Yb    = (bf16t*)(ws + 56623104);      //   overlay: 9216*2048 bf16 (after conv)
  float* dtraw = (float*)(ws + 96731136);      // 9216*16 f32
  float* dt    = (float*)(ws + 97320960);      // 9216*16 f32
  float* Acum  = (float*)(ws + 97910784);      // 64*9*256 f32
  bf16t* xbc   = (bf16t*)(ws + 98500608);      // 9216*2176 bf16
  bf16t* x2bf  = (bf16t*)(ws + 98500608);      //   overlay after ssd_y: 8192*1024 bf16
  bf16t* hbuf  = (bf16t*)(ws + 115277824);     //   overlay: 8192*512 bf16
  bf16t* outw_bf = (bf16t*)(ws + 123666432);   //   overlay: 1024*2048 bf16
  bf16t* f1w_bf  = (bf16t*)(ws + 127860736);   //   overlay: 512*1024 bf16
  bf16t* f2w_bf  = (bf16t*)(ws + 128909312);   //   overlay: 1024*512 bf16
  float* cs    = (float*)(ws + 138608640);     // 576*8192 f32
  bf16t* inpw_bf = (bf16t*)(ws + 138608640);   //   overlay BEFORE chunk_states

  ln_cvt_kernel<<<B_ * T_ + 4352, 256, 0, stream>>>(
      localr, globalr, n1w, n1b, n2w, n2b, x, inpw, inpw_bf);

  gemm_wide<0, false, 1024><<<dim3(NPROJ_PAD / 128, (B_ * T_) / 256), 512, 0, stream>>>(
      x, inpw_bf, nullptr, z, xpre, dtraw, nullptr, nullptr, nullptr, NPROJ_PAD);

  conv_cumsum_kernel<<<CONVBLKS + B_ * NH * NCHUNK, 256, 0, stream>>>(
      xpre, convw, convb, xbc, dtraw, dtb, alog, dt, Acum);

  chunk_states_kernel<<<B_ * (NCHUNK - 1) * NH, 256, 0, stream>>>(xbc, dt, Acum, cs);

  state_pass_kernel<<<dim3(B_ * NH, 8), 256, 0, stream>>>(cs, Acum);

  ssd_y_kernel<<<dim3(B_ * (NCHUNK - 1) * NH, 2), 256, 0, stream>>>(
      xbc, dt, Acum, cs, dskp, Yb);

  gate_rms_cvt_kernel<<<B_ * L_ + 3072, 256, 0, stream>>>(
      z, ssdw, Yb, outw, f1w, f2w, outw_bf, f1w_bf, f2w_bf);

  gemm_wide<1, true, 2048><<<dim3(DM / 128, (B_ * L_) / 256), 512, 0, stream>>>(
      Yb, outw_bf, mfull, nullptr, nullptr, nullptr, nullptr, nullptr, nullptr, DM);

  res_ln3_kernel<<<B_ * L_, 256, 0, stream>>>(mfull, x, n3w, n3b, x2bf);

  gemm_mfma<2><<<dim3((DM / 2) / 128, (B_ * L_) / 128), 256, 0, stream>>>(
      x2bf, f1w_bf, f1b, nullptr, nullptr, hbuf, DM / 2, DM);

  gemm_wide<2, false, 512><<<dim3(DM / 128, (B_ * L_) / 256), 512, 0, stream>>>(
      hbuf, f2w_bf, nullptr, nullptr, nullptr, nullptr, f2b, x2bf, (float*)d_out, DM);
}

// Round 10
// 445.349 us; speedup vs baseline: 1.0313x; 1.0043x over previous
//
#include <hip/hip_runtime.h>
#include <math.h>

#define B_ 4
#define L_ 2048
#define G_ 256
#define T_ 2304          // G_ + L_
#define DM 1024
#define DINNER 2048
#define NH 16
#define HD 128
#define NSTATE 64
#define CONVD 2176       // DINNER + 2*NSTATE
#define DPROJ 4240       // 2*DINNER + 2*NSTATE + NH
#define NPROJ_PAD 4352   // DPROJ padded to 128
#define NCHUNK 9
#define CK 256
#define EPSV 1e-5f
#define CROWS 16         // conv rows per thread
#define CONVBLKS 612     // (B_*T_/CROWS)*272/256

typedef unsigned short bf16t;
using bf16x8 = __attribute__((ext_vector_type(8))) short;
using f32x4  = __attribute__((ext_vector_type(4))) float;

__device__ __forceinline__ float bf2f(bf16t u) {
  return __uint_as_float(((unsigned int)u) << 16);
}
__device__ __forceinline__ bf16t f2bf(float f) {
  unsigned int u = __float_as_uint(f);
  u += 0x7FFFu + ((u >> 16) & 1u);
  return (bf16t)(u >> 16);
}

__device__ __forceinline__ void g2lds16(const bf16t* g, short* l) {
  __builtin_amdgcn_global_load_lds(
      (const __attribute__((address_space(1))) unsigned int*)g,
      (__attribute__((address_space(3))) unsigned int*)l, 16, 0, 0);
}

// XCD-chunked bijective block swizzle (requires gridDim.x*gridDim.y % 8 == 0).
__device__ __forceinline__ int2 xcd_swz(int tiles_n) {
  int gx = gridDim.x, gy = gridDim.y;
  int id = blockIdx.y * gx + blockIdx.x;
  int cpx = (gx * gy) >> 3;
  int L = (id & 7) * cpx + (id >> 3);
  return make_int2(L % tiles_n, L / tiles_n);   // (nhat, mhat)
}

// ---------- block-wide reduction of two values (blockDim == 256) ----------
__device__ __forceinline__ float2 block_reduce2(float a, float b) {
  __shared__ float sa[4], sb[4];
  #pragma unroll
  for (int off = 32; off > 0; off >>= 1) {
    a += __shfl_down(a, off, 64);
    b += __shfl_down(b, off, 64);
  }
  int lane = threadIdx.x & 63, wid = threadIdx.x >> 6;
  if (lane == 0) { sa[wid] = a; sb[wid] = b; }
  __syncthreads();
  return make_float2(sa[0] + sa[1] + sa[2] + sa[3], sb[0] + sb[1] + sb[2] + sb[3]);
}

// ---------- LN1/LN2+concat (blocks 0..9215) fused with in_proj weight cvt ----------
__global__ __launch_bounds__(256) void ln_cvt_kernel(
    const float* __restrict__ localr, const float* __restrict__ globalr,
    const float* __restrict__ w1, const float* __restrict__ b1,
    const float* __restrict__ w2, const float* __restrict__ b2,
    bf16t* __restrict__ x, const float* __restrict__ inpw,
    bf16t* __restrict__ inpw_bf) {
  int blk = blockIdx.x;
  if (blk < B_ * T_) {
    int t = blk % T_, b = blk / T_;
    const float *src, *w, *bb;
    if (t < G_) { src = globalr + ((long)b * G_ + t) * DM;        w = w2; bb = b2; }
    else        { src = localr  + ((long)b * L_ + (t - G_)) * DM; w = w1; bb = b1; }
    int d = threadIdx.x * 4;
    float4 v = *(const float4*)&src[d];
    float s = v.x + v.y + v.z + v.w;
    float sq = v.x * v.x + v.y * v.y + v.z * v.z + v.w * v.w;
    float2 r2 = block_reduce2(s, sq);
    float mu = r2.x * (1.f / DM);
    float var = r2.y * (1.f / DM) - mu * mu;
    float rstd = rsqrtf(var + EPSV);
    float4 wv = *(const float4*)&w[d];
    float4 bv = *(const float4*)&bb[d];
    ushort4 o;
    o.x = f2bf((v.x - mu) * rstd * wv.x + bv.x);
    o.y = f2bf((v.y - mu) * rstd * wv.y + bv.y);
    o.z = f2bf((v.z - mu) * rstd * wv.z + bv.z);
    o.w = f2bf((v.w - mu) * rstd * wv.w + bv.w);
    *(ushort4*)&x[(long)blk * DM + d] = o;
  } else {
    long i = (long)(blk - B_ * T_) * 1024 + threadIdx.x * 4;
    const long nreal = (long)DPROJ * DM, ntot = (long)NPROJ_PAD * DM;
    if (i < ntot) {
      ushort4 o = {0, 0, 0, 0};
      if (i < nreal) {
        float4 v = *(const float4*)&inpw[i];
        o.x = f2bf(v.x); o.y = f2bf(v.y); o.z = f2bf(v.z); o.w = f2bf(v.w);
      }
      *(ushort4*)&inpw_bf[i] = o;
    }
  }
}

// ---------- wide GEMM: 256x128 tile, 8 waves (4M x 2N), BK=32, SINGLE-phase ----------
// 2 blocks/CU (72 KiB LDS). A: 3 slots [256][32]; B: 3 slots [128][32], both
// staged 2 tiles ahead into slot (t+2)%3. ONE barrier per K-tile:
//   {stage(t+2); read slot t%3; 16 MFMA; vmcnt(3); barrier}
// Invariants: slot (t+2)%3's last reads were at top of tile t-1, before the
// end-of-(t-1) barrier that precedes this stage issue; vmcnt(3)+barrier makes
// tile t+1's 3 loads LDS-visible to all waves before tile t+1 reads them.
// Swizzle key = (row>>1)&3 (64B rows: bank-chunk = (4*row+g)%8; this key cycles
// all 4 values across same-parity rows -> 2-way conflicts, i.e. free).
// EPI 0: in_proj (z/xpre/dt routing); EPI 1: plain bf16 C (out_proj, OFFS remap);
// EPI 2: f32 C + bias + residual (ffn2 -> d_out).
template<int EPI, bool OFFS, int K>
__global__ __launch_bounds__(512, 4) void gemm_wide(
    const bf16t* __restrict__ A, const bf16t* __restrict__ W,
    bf16t* __restrict__ Cb, bf16t* __restrict__ z, bf16t* __restrict__ xpre,
    float* __restrict__ dtr, const float* __restrict__ bias,
    const bf16t* __restrict__ res, float* __restrict__ Cf, int N) {
  __shared__ short LDS8[36864];   // 72 KiB: A slots 0/8192/16384, B 24576+{0,4096,8192}
  int tid = threadIdx.x;
  int lane = tid & 63, w = tid >> 6;
  int wm = w >> 1, wn = w & 1;
  int l15 = lane & 15;
  int2 sz = xcd_swz(gridDim.x);
  int bn = sz.x * 128, bm = sz.y * 256;
  if (EPI == 0 && bn < DINNER && (bm % 2304) == 0) return;
  long bmA = OFFS ? ((long)(bm >> 11) * T_ + G_ + (bm & 2047)) : (long)bm;

  // staging: lane -> row_local = lane>>2, stored 16B-group = lane&3;
  // logical col group = (lane&3) ^ ((row>>1)&3) = (lane&3) ^ ((lane>>3)&3)
  int csub = ((lane & 3) ^ ((lane >> 3) & 3)) * 8;
  const bf16t* srcA = A + (bmA + w * 16 + (lane >> 2)) * (long)K + csub;
  const bf16t* srcW = W + (long)(bn + w * 16 + (lane >> 2)) * K + csub;
  int stageDst = w * 512 + lane * 8;     // shorts; wave covers 16 rows x 32 shorts

  // frag-read offset (shorts): row l15, stored group = (lane>>4) ^ ((l15>>1)&3)
  int off0 = l15 * 32 + (((lane >> 4) ^ ((l15 >> 1) & 3))) * 8;

  f32x4 acc[4][4] = {};
  bf16x8 af[4], bq[4];

#define STAGEA(gsrc, ldsoff) do { \
    g2lds16((gsrc), LDS8 + (ldsoff) + stageDst); \
    g2lds16((gsrc) + 128 * (long)K, LDS8 + (ldsoff) + stageDst + 4096); } while (0)
#define STAGEB(gsrc, ldsoff) g2lds16((gsrc), LDS8 + (ldsoff) + stageDst)

  // prologue: tiles 0 and 1; vmcnt(3) -> tile0's 3 loads landed (tile1's in flight)
  STAGEA(srcA, 0);
  STAGEB(srcW, 24576);
  STAGEA(srcA + 32, 8192);
  STAGEB(srcW + 32, 24576 + 4096);
  asm volatile("s_waitcnt vmcnt(3)" ::: "memory");
  __builtin_amdgcn_s_barrier();

  const int nt = K >> 5;
  for (int t = 0; t < nt; ++t) {
    const short* aB = LDS8 + (t % 3) * 8192 + wm * 2048;
    const short* bB = LDS8 + 24576 + (t % 3) * 4096 + wn * 2048;
    int nsA = ((t + 2) % 3) * 8192;
    int nsB = 24576 + ((t + 2) % 3) * 4096;

    // stage next-next tile first (loads get going under the reads/MFMA)
    if (t + 2 < nt) {
      STAGEA(srcA + (t + 2) * 32, nsA);
      STAGEB(srcW + (t + 2) * 32, nsB);
    }
    // read this tile's fragments
    #pragma unroll
    for (int mi = 0; mi < 4; mi++) af[mi] = *(const bf16x8*)&aB[mi * 512 + off0];
    #pragma unroll
    for (int ni = 0; ni < 4; ni++) bq[ni] = *(const bf16x8*)&bB[ni * 512 + off0];
    __builtin_amdgcn_s_setprio(1);
    #pragma unroll
    for (int mi = 0; mi < 4; mi++)
      #pragma unroll
      for (int ni = 0; ni < 4; ni++)
        acc[mi][ni] = __builtin_amdgcn_mfma_f32_16x16x32_bf16(af[mi], bq[ni], acc[mi][ni], 0, 0, 0);
    __builtin_amdgcn_s_setprio(0);
    if (t + 2 < nt)      asm volatile("s_waitcnt vmcnt(3)" ::: "memory");
    else if (t + 1 < nt) asm volatile("s_waitcnt vmcnt(0)" ::: "memory");
    __builtin_amdgcn_s_barrier();
  }
#undef STAGEA
#undef STAGEB

  // ---- epilogue ----
  if (EPI == 0 && bn == 4224) {
    if (wn == 0) {
      #pragma unroll
      for (int mi = 0; mi < 4; mi++)
        #pragma unroll
        for (int r = 0; r < 4; r++) {
          int row = bm + wm * 64 + mi * 16 + (lane >> 4) * 4 + r;
          dtr[(long)row * NH + l15] = acc[mi][0][r];
        }
    }
    return;
  }

  if (EPI == 2) {
    // f32 + bias + residual (ffn2): 4 passes of 64 rows (fits LDS)
    float* Cs32 = (float*)LDS8;               // [64][136] f32 = 34816 B
    #pragma unroll
    for (int pass = 0; pass < 4; pass++) {
      __syncthreads();
      if (wm == pass) {
        #pragma unroll
        for (int mi = 0; mi < 4; mi++)
          #pragma unroll
          for (int ni = 0; ni < 4; ni++)
            #pragma unroll
            for (int r = 0; r < 4; r++)
              Cs32[(mi * 16 + (lane >> 4) * 4 + r) * 136 + wn * 64 + ni * 16 + l15] =
                  acc[mi][ni][r];
      }
      __syncthreads();
      #pragma unroll
      for (int q = 0; q < 2; q++) {
        int idx = q * 512 + tid;             // 64 rows x 16 groups of 8 f32
        int row = idx >> 4, cg = (idx & 15) * 8;
        long grow = bm + pass * 64 + row; int gcol = bn + cg;
        float4 v0 = *(float4*)&Cs32[row * 136 + cg];
        float4 v1 = *(float4*)&Cs32[row * 136 + cg + 4];
        float4 b0 = *(const float4*)&bias[gcol];
        float4 b1 = *(const float4*)&bias[gcol + 4];
        bf16x8 rv = *(const bf16x8*)&res[grow * (long)N + gcol];
        v0.x += b0.x + bf2f((bf16t)rv[0]); v0.y += b0.y + bf2f((bf16t)rv[1]);
        v0.z += b0.z + bf2f((bf16t)rv[2]); v0.w += b0.w + bf2f((bf16t)rv[3]);
        v1.x += b1.x + bf2f((bf16t)rv[4]); v1.y += b1.y + bf2f((bf16t)rv[5]);
        v1.z += b1.z + bf2f((bf16t)rv[6]); v1.w += b1.w + bf2f((bf16t)rv[7]);
        *(float4*)&Cf[grow * (long)N + gcol] = v0;
        *(float4*)&Cf[grow * (long)N + gcol + 4] = v1;
      }
    }
    return;
  }

  // bf16 C via LDS roundtrip: 2 passes of 128 rows ([128][136] bf16 = 34816 B)
  bf16t* Cs = (bf16t*)LDS8;
  #pragma unroll
  for (int pass = 0; pass < 2; pass++) {
    __syncthreads();
    if ((wm >> 1) == pass) {
      #pragma unroll
      for (int mi = 0; mi < 4; mi++)
        #pragma unroll
        for (int ni = 0; ni < 4; ni++)
          #pragma unroll
          for (int r = 0; r < 4; r++)
            Cs[((wm & 1) * 64 + mi * 16 + (lane >> 4) * 4 + r) * 136 + wn * 64 + ni * 16 + l15] =
                f2bf(acc[mi][ni][r]);
    }
    __syncthreads();
    #pragma unroll
    for (int q = 0; q < 4; q++) {
      int idx = q * 512 + tid;
      int row = idx >> 4, cg = idx & 15;
      int gcol = bn + cg * 8;
      long grow = bm + pass * 128 + row;
      bf16x8 v = *(bf16x8*)&Cs[row * 136 + cg * 8];
      if (EPI == 0) {
        if (gcol < DINNER) *(bf16x8*)&z[grow * DINNER + gcol] = v;
        else               *(bf16x8*)&xpre[grow * CONVD + (gcol - DINNER)] = v;
      } else {
        *(bf16x8*)&Cb[grow * (long)N + gcol] = v;
      }
    }
  }
}

// ---------- MFMA bf16 GEMM 128x128 (ffn1: gelu(v+bias)) ----------
template<int EPI>
__global__ __launch_bounds__(256) void gemm_mfma(
    const bf16t* __restrict__ A, const bf16t* __restrict__ W,
    const float* __restrict__ bias, const bf16t* __restrict__ res,
    float* __restrict__ Cf, bf16t* __restrict__ Cb,
    int N, int K) {
  __shared__ __align__(16) short LDS[128 * 136];
  short* As = LDS;              // [128][32]
  short* Ws = LDS + 128 * 32;   // [128][32]
  int tid = threadIdx.x;
  int lane = tid & 63, w = tid >> 6;
  int wr = w >> 1, wc = w & 1;
  int2 sz = xcd_swz(gridDim.x);
  int bn = sz.x * 128, bm = sz.y * 128;

  int r1 = tid >> 2,         s1 = (((tid & 3) ^ ((r1 >> 1) & 3))) * 8;
  int r2 = (tid + 256) >> 2, s2 = (((tid & 3) ^ ((r2 >> 1) & 3))) * 8;
  const bf16t* gA1 = A + (long)(bm + r1) * K + s1;
  const bf16t* gA2 = A + (long)(bm + r2) * K + s2;
  const bf16t* gW1 = W + (long)(bn + r1) * K + s1;
  const bf16t* gW2 = W + (long)(bn + r2) * K + s2;
  short* lA1 = As + tid * 8;
  short* lA2 = As + (tid + 256) * 8;
  short* lW1 = Ws + tid * 8;
  short* lW2 = Ws + (tid + 256) * 8;

  int arow = wr * 64 + (lane & 15);
  int brow = wc * 64 + (lane & 15);
  int koff = (((lane >> 4) ^ (((lane & 15) >> 1) & 3))) * 8;

  f32x4 acc[4][4] = {};
  for (int k0 = 0; k0 < K; k0 += 32) {
    g2lds16(gA1 + k0, lA1);
    g2lds16(gA2 + k0, lA2);
    g2lds16(gW1 + k0, lW1);
    g2lds16(gW2 + k0, lW2);
    __syncthreads();
    bf16x8 af[4], bf[4];
    #pragma unroll
    for (int mi = 0; mi < 4; mi++) af[mi] = *(bf16x8*)&As[(arow + mi * 16) * 32 + koff];
    #pragma unroll
    for (int ni = 0; ni < 4; ni++) bf[ni] = *(bf16x8*)&Ws[(brow + ni * 16) * 32 + koff];
    #pragma unroll
    for (int mi = 0; mi < 4; mi++)
      #pragma unroll
      for (int ni = 0; ni < 4; ni++)
        acc[mi][ni] = __builtin_amdgcn_mfma_f32_16x16x32_bf16(af[mi], bf[ni], acc[mi][ni], 0, 0, 0);
    __syncthreads();
  }

  int rb = wr * 64 + (lane >> 4) * 4;
  int cb = wc * 64 + (lane & 15);

  __syncthreads();
  bf16t* Cs = (bf16t*)LDS;                     // [128][136]
  #pragma unroll
  for (int mi = 0; mi < 4; mi++)
    #pragma unroll
    for (int ni = 0; ni < 4; ni++)
      #pragma unroll
      for (int r = 0; r < 4; r++) {
        float v = acc[mi][ni][r];
        if (EPI == 2) {
          v += bias[bn + cb + ni * 16];
          v = 0.5f * v * (1.f + erff(v * 0.70710678118f));
        }
        Cs[(rb + mi * 16 + r) * 136 + cb + ni * 16] = f2bf(v);
      }
  __syncthreads();
  #pragma unroll
  for (int pass = 0; pass < 8; pass++) {
    int row = pass * 16 + (tid >> 4);
    int col = (tid & 15) * 8;
    bf16x8 vv = *(bf16x8*)&Cs[row * 136 + col];
    long grow = bm + row; int gcol = bn + col;
    *(bf16x8*)&Cb[grow * N + gcol] = vv;
  }
}

// ---------- merged: causal conv(4)+bias+silu  AND  dt softplus + chunk cumsum ----------
__global__ __launch_bounds__(256) void conv_cumsum_kernel(
    const bf16t* __restrict__ xpre, const float* __restrict__ cw,
    const float* __restrict__ cb, bf16t* __restrict__ out,
    const float* __restrict__ dtraw, const float* __restrict__ dt_bias,
    const float* __restrict__ A_log, float* __restrict__ dt,
    float* __restrict__ Acum) {
  if (blockIdx.x < CONVBLKS) {
    int gt = blockIdx.x * 256 + threadIdx.x;    // < 576*272
    int cg = gt % 272; int rt = gt / 272;
    int c0 = cg * 8;
    long r0 = (long)rt * CROWS;
    int t0 = (int)(r0 % T_);

    float wreg[4][8];
    #pragma unroll
    for (int j = 0; j < 8; j++) {
      float4 wa = *(const float4*)&cw[(c0 + j) * 4];
      wreg[0][j] = wa.x; wreg[1][j] = wa.y; wreg[2][j] = wa.z; wreg[3][j] = wa.w;
    }
    float4 cb0 = *(const float4*)&cb[c0];
    float4 cb1 = *(const float4*)&cb[c0 + 4];
    float bias[8] = {cb0.x, cb0.y, cb0.z, cb0.w, cb1.x, cb1.y, cb1.z, cb1.w};

    bf16x8 win[4];
    #pragma unroll
    for (int i = 0; i < 3; i++) {
      if (t0 - 3 + i >= 0) win[i] = *(const bf16x8*)&xpre[(r0 - 3 + i) * CONVD + c0];
      else                 win[i] = bf16x8{0,0,0,0,0,0,0,0};
    }

    #pragma unroll
    for (int k = 0; k < CROWS; k++) {
      win[3] = *(const bf16x8*)&xpre[(r0 + k) * CONVD + c0];
      float acc[8];
      #pragma unroll
      for (int j = 0; j < 8; j++) acc[j] = bias[j];
      #pragma unroll
      for (int i = 0; i < 4; i++)
        #pragma unroll
        for (int j = 0; j < 8; j++)
          acc[j] += bf2f((bf16t)win[i][j]) * wreg[i][j];
      bf16x8 o;
      #pragma unroll
      for (int j = 0; j < 8; j++) {
        float s = acc[j] / (1.f + __expf(-acc[j]));
        o[j] = (short)f2bf(s);
      }
      *(bf16x8*)&out[(r0 + k) * CONVD + c0] = o;
      win[0] = win[1]; win[1] = win[2]; win[2] = win[3];
    }
  } else {
    int bid = blockIdx.x - CONVBLKS;      // (b*NH+h)*NCHUNK + c
    int c = bid % NCHUNK; int hh = bid / NCHUNK;
    int h = hh % NH; int b = hh / NH;
    int k = threadIdx.x;
    float a = -__expf(A_log[h]);
    long t = (long)b * T_ + c * CK + k;
    float v0 = dtraw[t * NH + h] + dt_bias[h];
    float dtv = (v0 > 20.f) ? v0 : log1pf(__expf(v0));
    dt[t * NH + h] = dtv;
    float v = dtv * a;
    __shared__ float buf[2][CK];
    int cur = 0;
    buf[0][k] = v; __syncthreads();
    for (int off = 1; off < CK; off <<= 1) {
      float tv = buf[cur][k];
      if (k >= off) tv += buf[cur][k - off];
      buf[1 - cur][k] = tv; cur ^= 1; __syncthreads();
    }
    Acum[(long)bid * CK + k] = buf[cur][k];
  }
}

// ---------- per-chunk states via MFMA (chunks 0..7 only; chunk 8 unused) ----------
__global__ __launch_bounds__(256) void chunk_states_kernel(
    const bf16t* __restrict__ xbc, const float* __restrict__ dt,
    const float* __restrict__ Acum, float* __restrict__ cs) {
  int bid = blockIdx.x;                 // 512
  int h = bid & 15; int bc = bid >> 4;
  int c = bc & 7; int b = bc >> 3;
  int tid = threadIdx.x;
  int lane = tid & 63, w = tid >> 6;
  long tch = (long)b * T_ + c * CK;
  int acb = ((b * NH + h) * NCHUNK + c) * CK;
  float Alast = Acum[acb + CK - 1];

  __shared__ bf16t Xt[128][72];
  __shared__ bf16t Bt[64][72];
  __shared__ float wkv[256];
  // preload full chunk decay*dt weights once (replaces per-kb barrier+gather)
  wkv[tid] = __expf(Alast - Acum[acb + tid]) * dt[(tch + tid) * NH + h];

  f32x4 acc[8] = {};
  for (int kb = 0; kb < 4; kb++) {
    int s0 = kb * 64;
    __syncthreads();
    // Xt: 4-col packed ds_write_b64 transpose staging
    for (int e = tid; e < 16 * 32; e += 256) {
      int s4 = (e & 15) * 4, p4 = e >> 4;
      const bf16t* base = &xbc[(tch + s0 + s4) * CONVD + h * HD + p4 * 4];
      ushort4 u0 = *(const ushort4*)(base);
      ushort4 u1 = *(const ushort4*)(base + CONVD);
      ushort4 u2 = *(const ushort4*)(base + 2 * CONVD);
      ushort4 u3 = *(const ushort4*)(base + 3 * CONVD);
      float w0 = wkv[s0 + s4], w1 = wkv[s0 + s4 + 1];
      float w2 = wkv[s0 + s4 + 2], w3 = wkv[s0 + s4 + 3];
      ushort4 pk;
      pk.x = f2bf(bf2f(u0.x) * w0); pk.y = f2bf(bf2f(u1.x) * w1);
      pk.z = f2bf(bf2f(u2.x) * w2); pk.w = f2bf(bf2f(u3.x) * w3);
      *(ushort4*)&Xt[p4 * 4 + 0][s4] = pk;
      pk.x = f2bf(bf2f(u0.y) * w0); pk.y = f2bf(bf2f(u1.y) * w1);
      pk.z = f2bf(bf2f(u2.y) * w2); pk.w = f2bf(bf2f(u3.y) * w3);
      *(ushort4*)&Xt[p4 * 4 + 1][s4] = pk;
      pk.x = f2bf(bf2f(u0.z) * w0); pk.y = f2bf(bf2f(u1.z) * w1);
      pk.z = f2bf(bf2f(u2.z) * w2); pk.w = f2bf(bf2f(u3.z) * w3);
      *(ushort4*)&Xt[p4 * 4 + 2][s4] = pk;
      pk.x = f2bf(bf2f(u0.w) * w0); pk.y = f2bf(bf2f(u1.w) * w1);
      pk.z = f2bf(bf2f(u2.w) * w2); pk.w = f2bf(bf2f(u3.w) * w3);
      *(ushort4*)&Xt[p4 * 4 + 3][s4] = pk;
    }
    // Bt: same packing, no scale
    for (int e = tid; e < 16 * 16; e += 256) {
      int s4 = (e & 15) * 4, n4 = e >> 4;
      const bf16t* base = &xbc[(tch + s0 + s4) * CONVD + DINNER + n4 * 4];
      ushort4 u0 = *(const ushort4*)(base);
      ushort4 u1 = *(const ushort4*)(base + CONVD);
      ushort4 u2 = *(const ushort4*)(base + 2 * CONVD);
      ushort4 u3 = *(const ushort4*)(base + 3 * CONVD);
      ushort4 pk;
      pk.x = u0.x; pk.y = u1.x; pk.z = u2.x; pk.w = u3.x;
      *(ushort4*)&Bt[n4 * 4 + 0][s4] = pk;
      pk.x = u0.y; pk.y = u1.y; pk.z = u2.y; pk.w = u3.y;
      *(ushort4*)&Bt[n4 * 4 + 1][s4] = pk;
      pk.x = u0.z; pk.y = u1.z; pk.z = u2.z; pk.w = u3.z;
      *(ushort4*)&Bt[n4 * 4 + 2][s4] = pk;
      pk.x = u0.w; pk.y = u1.w; pk.z = u2.w; pk.w = u3.w;
      *(ushort4*)&Bt[n4 * 4 + 3][s4] = pk;
    }
    __syncthreads();
    #pragma unroll
    for (int ks = 0; ks < 2; ks++) {
      int koff = (lane >> 4) * 8 + ks * 32;
      bf16x8 bfr = *(bf16x8*)&Bt[w * 16 + (lane & 15)][koff];
      #pragma unroll
      for (int mi = 0; mi < 8; mi++) {
        bf16x8 af = *(bf16x8*)&Xt[mi * 16 + (lane & 15)][koff];
        acc[mi] = __builtin_amdgcn_mfma_f32_16x16x32_bf16(af, bfr, acc[mi], 0, 0, 0);
      }
    }
  }
  int cbid = (b * NCHUNK + c) * NH + h;
  float* out = cs + (long)cbid * HD * NSTATE;
  int n = w * 16 + (lane & 15);
  #pragma unroll
  for (int mi = 0; mi < 8; mi++) {
    #pragma unroll
    for (int r = 0; r < 4; r++) {
      int p = mi * 16 + (lane >> 4) * 4 + r;
      out[p * NSTATE + n] = acc[mi][r];
    }
  }
}

// ---------- sequential inter-chunk recurrence, IN PLACE ----------
__global__ __launch_bounds__(256) void state_pass_kernel(
    float* __restrict__ cs, const float* __restrict__ Acum) {
  int bh = blockIdx.x;                  // b*NH + h
  int b = bh / NH, h = bh % NH;
  int e0 = blockIdx.y * 1024 + threadIdx.x;
  for (int q = 0; q < 4; q++) {
    int e = e0 + q * 256;
    float s = 0.f;
    for (int c = 0; c < NCHUNK; c++) {
      long idx = ((long)(b * NCHUNK + c) * NH + h) * (HD * NSTATE) + e;
      if (c < NCHUNK - 1) {
        float tmp = cs[idx];
        cs[idx] = s;
        float g = __expf(Acum[((b * NH + h) * NCHUNK + c) * CK + CK - 1]);
        s = s * g + tmp;
      } else {
        cs[idx] = s;
      }
    }
  }
}

// ---------- SSD Y via MFMA (chunks 1..8; chunk 0's Y is discarded downstream) ----------
__global__ __launch_bounds__(256) void ssd_y_kernel(
    const bf16t* __restrict__ xbc, const float* __restrict__ dt,
    const float* __restrict__ Acum, const float* __restrict__ sin_,
    const float* __restrict__ Dskip, bf16t* __restrict__ Y) {
  int bid = blockIdx.x;                 // 512
  int h = bid & 15; int bc = bid >> 4;
  int c = 1 + (bc & 7); int b = bc >> 3;
  int rt = blockIdx.y;
  int tid = threadIdx.x;
  int lane = tid & 63, w = tid >> 6;
  int wr = w >> 1, wc = w & 1;
  long tch = (long)b * T_ + c * CK;
  long tbase = tch + rt * 128;
  int acb = ((b * NH + h) * NCHUNK + c) * CK;

  __shared__ bf16t Cs[128][72];
  __shared__ bf16t Bs[64][72];
  __shared__ __align__(16) bf16t XtSm[2][128][72];   // Xt | Sm; reused as f32 pad for Y-write
  bf16t (*Xt)[72] = XtSm[0];
  bf16t (*Sm)[72] = XtSm[1];
  __shared__ float Acv[256];
  __shared__ float dtv[256];

  for (int e = tid; e < 128 * 8; e += 256) {
    int row = e >> 3, seg = (e & 7) * 8;
    *(bf16x8*)&Cs[row][seg] =
        *(const bf16x8*)&xbc[(tbase + row) * CONVD + DINNER + NSTATE + seg];
  }
  // preload full chunk Acum and dt once (replaces per-sb barrier+gather)
  Acv[tid] = Acum[acb + tid];
  dtv[tid] = dt[(tch + tid) * NH + h];
  const float* Ak = Acv + rt * 128;

  f32x4 acc[4][4] = {};
  int nsb = 2 * (rt + 1);
  for (int sb = 0; sb < nsb; sb++) {
    int s0 = sb * 64;
    __syncthreads();
    for (int e = tid; e < 64 * 8; e += 256) {
      int row = e >> 3, seg = (e & 7) * 8;
      *(bf16x8*)&Bs[row][seg] =
          *(const bf16x8*)&xbc[(tch + s0 + row) * CONVD + DINNER + seg];
    }
    // Xt: 4-col packed ds_write_b64 transpose staging (scaled by dt)
    for (int e = tid; e < 16 * 32; e += 256) {
      int s4 = (e & 15) * 4, p4 = e >> 4;
      const bf16t* base = &xbc[(tch + s0 + s4) * CONVD + h * HD + p4 * 4];
      ushort4 u0 = *(const ushort4*)(base);
      ushort4 u1 = *(const ushort4*)(base + CONVD);
      ushort4 u2 = *(const ushort4*)(base + 2 * CONVD);
      ushort4 u3 = *(const ushort4*)(base + 3 * CONVD);
      float d0 = dtv[s0 + s4], d1 = dtv[s0 + s4 + 1];
      float d2 = dtv[s0 + s4 + 2], d3 = dtv[s0 + s4 + 3];
      ushort4 pk;
      pk.x = f2bf(bf2f(u0.x) * d0); pk.y = f2bf(bf2f(u1.x) * d1);
      pk.z = f2bf(bf2f(u2.x) * d2); pk.w = f2bf(bf2f(u3.x) * d3);
      *(ushort4*)&Xt[p4 * 4 + 0][s4] = pk;
      pk.x = f2bf(bf2f(u0.y) * d0); pk.y = f2bf(bf2f(u1.y) * d1);
      pk.z = f2bf(bf2f(u2.y) * d2); pk.w = f2bf(bf2f(u3.y) * d3);
      *(ushort4*)&Xt[p4 * 4 + 1][s4] = pk;
      pk.x = f2bf(bf2f(u0.z) * d0); pk.y = f2bf(bf2f(u1.z) * d1);
      pk.z = f2bf(bf2f(u2.z) * d2); pk.w = f2bf(bf2f(u3.z) * d3);
      *(ushort4*)&Xt[p4 * 4 + 2][s4] = pk;
      pk.x = f2bf(bf2f(u0.w) * d0); pk.y = f2bf(bf2f(u1.w) * d1);
      pk.z = f2bf(bf2f(u2.w) * d2); pk.w = f2bf(bf2f(u3.w) * d3);
      *(ushort4*)&Xt[p4 * 4 + 3][s4] = pk;
    }
    __syncthreads();
    {
      f32x4 sacc[2][4] = {};
      int rw0 = w * 32;
      #pragma unroll
      for (int ks = 0; ks < 2; ks++) {
        int koff = (lane >> 4) * 8 + ks * 32;
        bf16x8 a0 = *(bf16x8*)&Cs[rw0 + (lane & 15)][koff];
        bf16x8 a1 = *(bf16x8*)&Cs[rw0 + 16 + (lane & 15)][koff];
        #pragma unroll
        for (int ni = 0; ni < 4; ni++) {
          bf16x8 bfr = *(bf16x8*)&Bs[ni * 16 + (lane & 15)][koff];
          sacc[0][ni] = __builtin_amdgcn_mfma_f32_16x16x32_bf16(a0, bfr, sacc[0][ni], 0, 0, 0);
          sacc[1][ni] = __builtin_amdgcn_mfma_f32_16x16x32_bf16(a1, bfr, sacc[1][ni], 0, 0, 0);
        }
      }
      #pragma unroll
      for (int mi = 0; mi < 2; mi++) {
        #pragma unroll
        for (int ni = 0; ni < 4; ni++) {
          #pragma unroll
          for (int r = 0; r < 4; r++) {
            int row = rw0 + mi * 16 + (lane >> 4) * 4 + r;
            int scol = ni * 16 + (lane & 15);
            int kglob = rt * 128 + row;
            int sglob = s0 + scol;
            float val = 0.f;
            if (sglob <= kglob) val = sacc[mi][ni][r] * __expf(Ak[row] - Acv[s0 + scol]);
            Sm[row][scol] = f2bf(val);
          }
        }
      }
    }
    __syncthreads();
    #pragma unroll
    for (int ks = 0; ks < 2; ks++) {
      int koff = (lane >> 4) * 8 + ks * 32;
      bf16x8 af[4], bfr[4];
      #pragma unroll
      for (int mi = 0; mi < 4; mi++) af[mi] = *(bf16x8*)&Sm[wr * 64 + mi * 16 + (lane & 15)][koff];
      #pragma unroll
      for (int ni = 0; ni < 4; ni++) bfr[ni] = *(bf16x8*)&Xt[wc * 64 + ni * 16 + (lane & 15)][koff];
      #pragma unroll
      for (int mi = 0; mi < 4; mi++)
        #pragma unroll
        for (int ni = 0; ni < 4; ni++)
          acc[mi][ni] = __builtin_amdgcn_mfma_f32_16x16x32_bf16(af[mi], bfr[ni], acc[mi][ni], 0, 0, 0);
    }
  }

  float ekr[16];
  #pragma unroll
  for (int mi = 0; mi < 4; mi++)
    #pragma unroll
    for (int r = 0; r < 4; r++)
      ekr[mi * 4 + r] = __expf(Ak[wr * 64 + mi * 16 + (lane >> 4) * 4 + r]);

  int cbid = (b * NCHUNK + c) * NH + h;
  const float* sinb = sin_ + (long)cbid * HD * NSTATE;
  #pragma unroll
  for (int ni = 0; ni < 4; ni++) {
    f32x4 offacc[4] = {};
    int p = wc * 64 + ni * 16 + (lane & 15);
    #pragma unroll
    for (int ks = 0; ks < 2; ks++) {
      int koff = (lane >> 4) * 8 + ks * 32;
      const float* srow = sinb + p * NSTATE + koff;
      float4 sa = *(const float4*)srow;
      float4 sbv = *(const float4*)(srow + 4);
      bf16x8 bfr;
      bfr[0] = (short)f2bf(sa.x);  bfr[1] = (short)f2bf(sa.y);
      bfr[2] = (short)f2bf(sa.z);  bfr[3] = (short)f2bf(sa.w);
      bfr[4] = (short)f2bf(sbv.x); bfr[5] = (short)f2bf(sbv.y);
      bfr[6] = (short)f2bf(sbv.z); bfr[7] = (short)f2bf(sbv.w);
      #pragma unroll
      for (int mi = 0; mi < 4; mi++) {
        bf16x8 af = *(bf16x8*)&Cs[wr * 64 + mi * 16 + (lane & 15)][koff];
        offacc[mi] = __builtin_amdgcn_mfma_f32_16x16x32_bf16(af, bfr, offacc[mi], 0, 0, 0);
      }
    }
    #pragma unroll
    for (int mi = 0; mi < 4; mi++)
      #pragma unroll
      for (int r = 0; r < 4; r++)
        acc[mi][ni][r] += ekr[mi * 4 + r] * offacc[mi][r];
  }

  // ---- vectorized Y write: acc (f32) through LDS (dead Xt+Sm), bf16x8 IO ----
  float dsk = Dskip[h];
  float* Sf = (float*)&XtSm[0][0][0];          // [64][130] f32 (33280 B <= 36864)
  #pragma unroll
  for (int rh = 0; rh < 2; rh++) {
    __syncthreads();
    if (wr == rh) {
      #pragma unroll
      for (int mi = 0; mi < 4; mi++)
        #pragma unroll
        for (int ni = 0; ni < 4; ni++)
          #pragma unroll
          for (int r = 0; r < 4; r++)
            Sf[(mi * 16 + (lane >> 4) * 4 + r) * 130 + wc * 64 + ni * 16 + (lane & 15)] =
                acc[mi][ni][r];
    }
    __syncthreads();
    #pragma unroll
    for (int g = 0; g < 4; g++) {
      int idx = g * 256 + tid;                 // 64 rows x 16 col-groups
      int row = idx >> 4, cg = (idx & 15) * 8;
      long t = tbase + rh * 64 + row;
      bf16x8 xv = *(const bf16x8*)&xbc[t * CONVD + h * HD + cg];
      bf16x8 o;
      #pragma unroll
      for (int j = 0; j < 8; j++)
        o[j] = (short)f2bf(Sf[row * 130 + cg + j] + dsk * bf2f((bf16t)xv[j]));
      *(bf16x8*)&Y[t * DINNER + h * HD + cg] = o;
    }
  }
}

// ---------- gate+RMSNorm (local rows only) fused with late weight cvt ----------
__global__ __launch_bounds__(256) void gate_rms_cvt_kernel(
    const bf16t* __restrict__ z, const float* __restrict__ nw,
    bf16t* __restrict__ Y,
    const float* __restrict__ outw, const float* __restrict__ f1w,
    const float* __restrict__ f2w, bf16t* __restrict__ o_out,
    bf16t* __restrict__ o_f1, bf16t* __restrict__ o_f2) {
  int blk = blockIdx.x;
  if (blk < B_ * L_) {
    long r = (long)(blk >> 11) * T_ + G_ + (blk & 2047);
    const bf16t* zrow = z + r * DINNER;
    bf16t* yrow = Y + r * DINNER;
    int tid = threadIdx.x;
    int d = tid * 8;
    bf16x8 zu = *(const bf16x8*)&zrow[d];
    bf16x8 yu = *(const bf16x8*)&yrow[d];
    float v[8]; float sq = 0.f;
    #pragma unroll
    for (int j = 0; j < 8; j++) {
      float z0 = bf2f((bf16t)zu[j]);
      float y0 = bf2f((bf16t)yu[j]) * (z0 / (1.f + __expf(-z0)));
      v[j] = y0; sq += y0 * y0;
    }
    float2 r2 = block_reduce2(sq, 0.f);
    float rms = rsqrtf(r2.x * (1.f / DINNER) + EPSV);
    float4 nw0 = *(const float4*)&nw[d];
    float4 nw1 = *(const float4*)&nw[d + 4];
    float nn[8] = {nw0.x, nw0.y, nw0.z, nw0.w, nw1.x, nw1.y, nw1.z, nw1.w};
    bf16x8 o;
    #pragma unroll
    for (int j = 0; j < 8; j++) o[j] = (short)f2bf(v[j] * rms * nn[j]);
    *(bf16x8*)&yrow[d] = o;
  } else {
    long i = (long)(blk - B_ * L_) * 1024 + threadIdx.x * 4;
    const long n1 = (long)DM * DINNER;          // 2097152
    const long n2 = (long)(DM / 2) * DM;        // 524288
    const float* src; bf16t* dst; long off;
    if (i < n1) { src = outw; dst = o_out; off = i; }
    else if (i < n1 + n2) { src = f1w; dst = o_f1; off = i - n1; }
    else { src = f2w; dst = o_f2; off = i - n1 - n2; }
    float4 v = *(const float4*)&src[off];
    ushort4 o;
    o.x = f2bf(v.x); o.y = f2bf(v.y); o.z = f2bf(v.z); o.w = f2bf(v.w);
    *(ushort4*)&dst[off] = o;
  }
}

// ---------- residual add + LayerNorm3 -> bf16 (mfull compact [8192][1024]) ----------
__global__ __launch_bounds__(256) void res_ln3_kernel(
    const bf16t* __restrict__ mfull, const bf16t* __restrict__ x,
    const float* __restrict__ w3, const float* __restrict__ b3,
    bf16t* __restrict__ x2) {
  int rl = blockIdx.x;                  // b*L_ + tl
  int tl = rl & 2047, b = rl >> 11;
  long rt = (long)b * T_ + G_ + tl;
  const bf16t* m = mfull + (long)rl * DM;
  const bf16t* xr = x + rt * DM;
  int tid = threadIdx.x;
  int d = tid * 4;
  ushort4 mu4 = *(const ushort4*)&m[d];
  ushort4 xu4 = *(const ushort4*)&xr[d];
  float v[4];
  v[0] = bf2f(mu4.x) + bf2f(xu4.x);
  v[1] = bf2f(mu4.y) + bf2f(xu4.y);
  v[2] = bf2f(mu4.z) + bf2f(xu4.z);
  v[3] = bf2f(mu4.w) + bf2f(xu4.w);
  float s = v[0] + v[1] + v[2] + v[3];
  float sq = v[0]*v[0] + v[1]*v[1] + v[2]*v[2] + v[3]*v[3];
  float2 r2 = block_reduce2(s, sq);
  float mu = r2.x * (1.f / DM);
  float var = r2.y * (1.f / DM) - mu * mu;
  float rstd = rsqrtf(var + EPSV);
  float4 w4 = *(const float4*)&w3[d];
  float4 b4 = *(const float4*)&b3[d];
  ushort4 o;
  o.x = f2bf((v[0] - mu) * rstd * w4.x + b4.x);
  o.y = f2bf((v[1] - mu) * rstd * w4.y + b4.y);
  o.z = f2bf((v[2] - mu) * rstd * w4.z + b4.z);
  o.w = f2bf((v[3] - mu) * rstd * w4.w + b4.w);
  *(ushort4*)&x2[(long)rl * DM + d] = o;
}

extern "C" void kernel_launch(void* const* d_in, const int* in_sizes, int n_in,
                              void* d_out, int out_size, void* d_ws, size_t ws_size,
                              hipStream_t stream) {
  const float* localr = (const float*)d_in[0];
  const float* globalr= (const float*)d_in[1];
  const float* n1w = (const float*)d_in[2];
  const float* n1b = (const float*)d_in[3];
  const float* n2w = (const float*)d_in[4];
  const float* n2b = (const float*)d_in[5];
  const float* n3w = (const float*)d_in[6];
  const float* n3b = (const float*)d_in[7];
  const float* inpw= (const float*)d_in[8];
  const float* convw=(const float*)d_in[9];
  const float* convb=(const float*)d_in[10];
  const float* dtb = (const float*)d_in[11];
  const float* alog= (const float*)d_in[12];
  const float* dskp= (const float*)d_in[13];
  const float* ssdw= (const float*)d_in[14];
  const float* outw= (const float*)d_in[15];
  const float* f1w = (const float*)d_in[16];
  const float* f1b = (const float*)d_in[17];
  const float* f2w = (const float*)d_in[18];
  const float* f2b = (const float*)d_in[19];

  // ---- workspace layout (byte offsets); peak ~150 MB ----
  char* ws = (char*)d_ws;
  bf16t* x     = (bf16t*)(ws + 0);             // 9216*1024 bf16
  bf16t* z     = (bf16t*)(ws + 18874368);      // 9216*2048 bf16
  bf16t* mfull = (bf16t*)(ws + 18874368);      //   overlay: 8192*1024 bf16 compact
  bf16t* xpre  = (bf16t*)(ws + 56623104);      // 9216*2176 bf16
  bf16t* Yb    = (bf16t*)(ws + 56623104);      //   overlay: 9216*2048 bf16 (after conv)
  float* dtraw = (float*)(ws + 96731136);      // 9216*16 f32
  float* dt    = (float*)(ws + 97320960);      // 9216*16 f32
  float* Acum  = (float*)(ws + 97910784);      // 64*9*256 f32
  bf16t* xbc   = (bf16t*)(ws + 98500608);      // 9216*2176 bf16
  bf16t* x2bf  = (bf16t*)(ws + 98500608);      //   overlay after ssd_y: 8192*1024 bf16
  bf16t* hbuf  = (bf16t*)(ws + 115277824);     //   overlay: 8192*512 bf16
  bf16t* outw_bf = (bf16t*)(ws + 123666432);   //   overlay: 1024*2048 bf16
  bf16t* f1w_bf  = (bf16t*)(ws + 127860736);   //   overlay: 512*1024 bf16
  bf16t* f2w_bf  = (bf16t*)(ws + 128909312);   //   overlay: 1024*512 bf16
  float* cs    = (float*)(ws + 138608640);     // 576*8192 f32
  bf16t* inpw_bf = (bf16t*)(ws + 138608640);   //   overlay BEFORE chunk_states

  ln_cvt_kernel<<<B_ * T_ + 4352, 256, 0, stream>>>(
      localr, globalr, n1w, n1b, n2w, n2b, x, inpw, inpw_bf);

  gemm_wide<0, false, 1024><<<dim3(NPROJ_PAD / 128, (B_ * T_) / 256), 512, 0, stream>>>(
      x, inpw_bf, nullptr, z, xpre, dtraw, nullptr, nullptr, nullptr, NPROJ_PAD);

  conv_cumsum_kernel<<<CONVBLKS + B_ * NH * NCHUNK, 256, 0, stream>>>(
      xpre, convw, convb, xbc, dtraw, dtb, alog, dt, Acum);

  chunk_states_kernel<<<B_ * (NCHUNK - 1) * NH, 256, 0, stream>>>(xbc, dt, Acum, cs);

  state_pass_kernel<<<dim3(B_ * NH, 8), 256, 0, stream>>>(cs, Acum);

  ssd_y_kernel<<<dim3(B_ * (NCHUNK - 1) * NH, 2), 256, 0, stream>>>(
      xbc, dt, Acum, cs, dskp, Yb);

  gate_rms_cvt_kernel<<<B_ * L_ + 3072, 256, 0, stream>>>(
      z, ssdw, Yb, outw, f1w, f2w, outw_bf, f1w_bf, f2w_bf);

  gemm_wide<1, true, 2048><<<dim3(DM / 128, (B_ * L_) / 256), 512, 0, stream>>>(
      Yb, outw_bf, mfull, nullptr, nullptr, nullptr, nullptr, nullptr, nullptr, DM);

  res_ln3_kernel<<<B_ * L_, 256, 0, stream>>>(mfull, x, n3w, n3b, x2bf);

  gemm_mfma<2><<<dim3((DM / 2) / 128, (B_ * L_) / 128), 256, 0, stream>>>(
      x2bf, f1w_bf, f1b, nullptr, nullptr, hbuf, DM / 2, DM);

  gemm_wide<2, false, 512><<<dim3(DM / 128, (B_ * L_) / 256), 512, 0, stream>>>(
      hbuf, f2w_bf, nullptr, nullptr, nullptr, nullptr, f2b, x2bf, (float*)d_out, DM);
}